// Round 1
// baseline (246.355 us; speedup 1.0000x reference)
//
#include <hip/hip_runtime.h>

#define B_ 1024
#define L_ 1024
#define NCAT_ 20
#define NNUM_ 10
#define E_ 32
#define A_ 128
#define H_ 256
#define TOPK_ 30
#define INV_SQRT_A 0.08838834764831845f

// ---------------------------------------------------------------------------
// K1: per-row prep. One block (128 threads) per batch row.
//   p_b      = Wk @ (tgt_e @ Wq)          [B,32]  (score projection)
//   fused[0:32]  = tgt_e
//   fused[64:96] = cat_pool
//   fused[96:128]= num_e
// ---------------------------------------------------------------------------
__global__ __launch_bounds__(128) void prep_kernel(
    const int* __restrict__ cats, const float* __restrict__ nums,
    const int* __restrict__ tgt_ids, const float* __restrict__ cat_emb,
    const float* __restrict__ Wnum, const float* __restrict__ bnum,
    const float* __restrict__ Wq, const float* __restrict__ Wk,
    const float* __restrict__ Wpool, const float* __restrict__ bpool,
    float* __restrict__ p_out, float* __restrict__ fused)
{
    const int b = blockIdx.x;
    const int t = threadIdx.x;

    __shared__ float tgt_e[E_];
    __shared__ float qv[A_];
    __shared__ float ce[NCAT_ * E_];      // 640
    __shared__ float psum[4][E_];

    if (t < E_) tgt_e[t] = cat_emb[(long)tgt_ids[b] * E_ + t];
    for (int i = t; i < NCAT_ * E_; i += 128) {
        int c = i >> 5, e = i & 31;
        ce[i] = cat_emb[(long)cats[b * NCAT_ + c] * E_ + e];
    }
    __syncthreads();

    // q[a] = tgt_e . Wq[:,a]   (a = t, 128 threads)
    float qa = 0.f;
#pragma unroll
    for (int e = 0; e < E_; ++e) qa += tgt_e[e] * Wq[e * A_ + t];
    qv[t] = qa;

    // cat_pool partials: 4 groups of 32 threads, 160 inputs each
    const int j = t & 31, g = t >> 5;
    float cp = 0.f;
    const int i0 = g * 160;
    for (int i = i0; i < i0 + 160; ++i) cp += ce[i] * Wpool[i * E_ + j];
    psum[g][j] = cp;
    __syncthreads();

    if (t < E_) {
        // p[e] = sum_a Wk[e,a] * q[a]
        float s = 0.f;
#pragma unroll 8
        for (int a = 0; a < A_; ++a) s += Wk[t * A_ + a] * qv[a];
        p_out[b * E_ + t] = s;

        fused[b * 128 + t] = tgt_e[t];

        float ne = bnum[t];
#pragma unroll
        for (int n = 0; n < NNUM_; ++n) ne += nums[b * NNUM_ + n] * Wnum[n * E_ + t];
        fused[b * 128 + 96 + t] = ne;

        fused[b * 128 + 64 + t] = psum[0][t] + psum[1][t] + psum[2][t] + psum[3][t] + bpool[t];
    }
}

// ---------------------------------------------------------------------------
// K2: scores[b,l] = (p_b . seq_emb[seqs[b,l]]) / sqrt(A)
// grid = B*L/256 blocks of 256 threads; 4 blocks per batch row.
// ---------------------------------------------------------------------------
__global__ __launch_bounds__(256) void score_kernel(
    const int* __restrict__ seqs, const float* __restrict__ seq_emb,
    const float* __restrict__ p, float* __restrict__ scores)
{
    const int b = blockIdx.x >> 2;
    const int l = ((blockIdx.x & 3) << 8) | threadIdx.x;

    __shared__ float ps[E_];
    if (threadIdx.x < E_) ps[threadIdx.x] = p[b * E_ + threadIdx.x];
    __syncthreads();

    const int tok = seqs[b * L_ + l];
    const float4* er = (const float4*)(seq_emb + (long)tok * E_);
    float acc = 0.f;
#pragma unroll
    for (int i = 0; i < 8; ++i) {
        float4 v = er[i];
        acc += v.x * ps[4 * i] + v.y * ps[4 * i + 1] + v.z * ps[4 * i + 2] + v.w * ps[4 * i + 3];
    }
    scores[b * L_ + l] = acc * INV_SQRT_A;
}

// ---------------------------------------------------------------------------
// K3: per-row top-30 -> softmax -> ebar = sum w_k * e_k ->
//     interest = (ebar @ Wv) @ Wo + bo  -> fused[32:64]
// One block (256 threads) per batch row.
// ---------------------------------------------------------------------------
__global__ __launch_bounds__(256) void topk_kernel(
    const int* __restrict__ seqs, const float* __restrict__ seq_emb,
    const float* __restrict__ scores, const float* __restrict__ Wv,
    const float* __restrict__ Wo, const float* __restrict__ bo,
    float* __restrict__ fused)
{
    const int b = blockIdx.x;
    const int t = threadIdx.x;
    const int lane = t & 63, wave = t >> 6;

    __shared__ float sc[L_];
    __shared__ float rv[4];
    __shared__ int   ri[4];
    __shared__ float selv[TOPK_];
    __shared__ int   seli[TOPK_];
    __shared__ float wsoft[TOPK_];
    __shared__ float ebar[E_];
    __shared__ float uA[A_];

    for (int i = t; i < L_; i += 256) sc[i] = scores[b * L_ + i];
    __syncthreads();

    for (int k = 0; k < TOPK_; ++k) {
        float best = -1e30f; int bi = 0;
#pragma unroll
        for (int jj = 0; jj < 4; ++jj) {
            int j = t + jj * 256;
            float v = sc[j];
            if (v > best) { best = v; bi = j; }
        }
        // wave-level argmax reduce
#pragma unroll
        for (int off = 32; off > 0; off >>= 1) {
            float ov = __shfl_down(best, off);
            int   oi = __shfl_down(bi, off);
            if (ov > best) { best = ov; bi = oi; }
        }
        if (lane == 0) { rv[wave] = best; ri[wave] = bi; }
        __syncthreads();
        if (t == 0) {
            float bb = rv[0]; int bbi = ri[0];
#pragma unroll
            for (int w = 1; w < 4; ++w)
                if (rv[w] > bb) { bb = rv[w]; bbi = ri[w]; }
            selv[k] = bb; seli[k] = bbi;
            sc[bbi] = -1e30f;
        }
        __syncthreads();
    }

    // softmax over top-30 (wave 0)
    if (wave == 0) {
        float v = (lane < TOPK_) ? selv[lane] : -1e30f;
        float m = v;
#pragma unroll
        for (int off = 32; off > 0; off >>= 1) m = fmaxf(m, __shfl_down(m, off));
        m = __shfl(m, 0);
        float e = (lane < TOPK_) ? __expf(v - m) : 0.f;
        // use precise expf for accuracy
        e = (lane < TOPK_) ? expf(v - m) : 0.f;
        float s = e;
#pragma unroll
        for (int off = 32; off > 0; off >>= 1) s += __shfl_down(s, off);
        s = __shfl(s, 0);
        if (lane < TOPK_) wsoft[lane] = e / s;
    }
    __syncthreads();

    // ebar[e] = sum_k w_k * seq_emb[tok_k][e]
    if (t < E_) {
        float acc = 0.f;
        for (int k = 0; k < TOPK_; ++k) {
            int tok = seqs[b * L_ + seli[k]];
            acc += wsoft[k] * seq_emb[(long)tok * E_ + t];
        }
        ebar[t] = acc;
    }
    __syncthreads();

    // uA[a] = ebar @ Wv
    if (t < A_) {
        float acc = 0.f;
#pragma unroll
        for (int e = 0; e < E_; ++e) acc += ebar[e] * Wv[e * A_ + t];
        uA[t] = acc;
    }
    __syncthreads();

    // interest[j] = uA @ Wo + bo
    if (t < E_) {
        float acc = bo[t];
#pragma unroll 8
        for (int a = 0; a < A_; ++a) acc += uA[a] * Wo[a * E_ + t];
        fused[b * 128 + 32 + t] = acc;
    }
}

// ---------------------------------------------------------------------------
// K4: MLP chain: h = relu(fused@Wmlp+bmlp); 2x qnn; out = h@Wout+bout
// 256 blocks x 256 threads; each block handles R=4 rows, streams weights.
// ---------------------------------------------------------------------------
#define R_ 4
__global__ __launch_bounds__(256) void mlp_kernel(
    const float* __restrict__ fused,
    const float* __restrict__ Wmlp, const float* __restrict__ bmlp,
    const float* __restrict__ W11, const float* __restrict__ b11,
    const float* __restrict__ W12, const float* __restrict__ b12,
    const float* __restrict__ W1p, const float* __restrict__ b1p,
    const float* __restrict__ W21, const float* __restrict__ b21,
    const float* __restrict__ W22, const float* __restrict__ b22,
    const float* __restrict__ W2p, const float* __restrict__ b2p,
    const float* __restrict__ Wout, const float* __restrict__ bout,
    float* __restrict__ out)
{
    const int b0 = blockIdx.x * R_;
    const int t = threadIdx.x;

    __shared__ float xs[R_][128];
    __shared__ float hs[R_][H_];
    __shared__ float ts[R_][H_];
    __shared__ float red[256];

    for (int i = t; i < R_ * 128; i += 256) xs[i >> 7][i & 127] = fused[b0 * 128 + i];
    __syncthreads();

    // stage 1: h = relu(x @ Wmlp + bmlp)
    {
        float acc[R_];
        float bm = bmlp[t];
#pragma unroll
        for (int r = 0; r < R_; ++r) acc[r] = bm;
        for (int i = 0; i < 128; ++i) {
            float w = Wmlp[i * H_ + t];
#pragma unroll
            for (int r = 0; r < R_; ++r) acc[r] += xs[r][i] * w;
        }
#pragma unroll
        for (int r = 0; r < R_; ++r) hs[r][t] = fmaxf(acc[r], 0.f);
    }
    __syncthreads();

    // two qnn blocks
    const float* W1s[2] = { W11, W21 };
    const float* b1s[2] = { b11, b21 };
    const float* W2s[2] = { W12, W22 };
    const float* b2s[2] = { b12, b22 };
    const float* Wps[2] = { W1p, W2p };
    const float* bps[2] = { b1p, b2p };

    for (int q = 0; q < 2; ++q) {
        const float* W1 = W1s[q]; const float* W2 = W2s[q]; const float* Wp = Wps[q];
        float a1[R_], a2[R_];
        float bb1 = b1s[q][t], bb2 = b2s[q][t];
#pragma unroll
        for (int r = 0; r < R_; ++r) { a1[r] = bb1; a2[r] = bb2; }
        for (int i = 0; i < H_; ++i) {
            float w1 = W1[i * H_ + t];
            float w2 = W2[i * H_ + t];
#pragma unroll
            for (int r = 0; r < R_; ++r) {
                float x = hs[r][i];
                a1[r] += x * w1;
                a2[r] += x * w2;
            }
        }
#pragma unroll
        for (int r = 0; r < R_; ++r) ts[r][t] = a1[r] * a2[r];
        __syncthreads();

        float ap[R_];
        float bbp = bps[q][t];
#pragma unroll
        for (int r = 0; r < R_; ++r) ap[r] = bbp;
        for (int i = 0; i < H_; ++i) {
            float wp = Wp[i * H_ + t];
#pragma unroll
            for (int r = 0; r < R_; ++r) ap[r] += ts[r][i] * wp;
        }
#pragma unroll
        for (int r = 0; r < R_; ++r) hs[r][t] = hs[r][t] + ap[r];
        __syncthreads();
    }

    // output: out[r] = hs[r] . Wout + bout
    float wo = Wout[t];
    for (int r = 0; r < R_; ++r) {
        red[t] = hs[r][t] * wo;
        __syncthreads();
#pragma unroll
        for (int s = 128; s > 0; s >>= 1) {
            if (t < s) red[t] += red[t + s];
            __syncthreads();
        }
        if (t == 0) out[b0 + r] = red[0] + bout[0];
        __syncthreads();
    }
}

// ---------------------------------------------------------------------------
extern "C" void kernel_launch(void* const* d_in, const int* in_sizes, int n_in,
                              void* d_out, int out_size, void* d_ws, size_t ws_size,
                              hipStream_t stream) {
    const int*   cats    = (const int*)d_in[0];
    const float* nums    = (const float*)d_in[1];
    const int*   seqs    = (const int*)d_in[2];
    const int*   tgt_ids = (const int*)d_in[3];
    const float* cat_emb = (const float*)d_in[4];
    const float* seq_emb = (const float*)d_in[5];
    const float* Wnum    = (const float*)d_in[6];
    const float* bnum    = (const float*)d_in[7];
    const float* Wq      = (const float*)d_in[8];
    const float* Wk      = (const float*)d_in[9];
    const float* Wv      = (const float*)d_in[10];
    const float* Wo      = (const float*)d_in[11];
    const float* bo      = (const float*)d_in[12];
    const float* Wpool   = (const float*)d_in[13];
    const float* bpool   = (const float*)d_in[14];
    const float* Wmlp    = (const float*)d_in[15];
    const float* bmlp    = (const float*)d_in[16];
    const float* q1_W1   = (const float*)d_in[17];
    const float* q1_b1   = (const float*)d_in[18];
    const float* q1_W2   = (const float*)d_in[19];
    const float* q1_b2   = (const float*)d_in[20];
    const float* q1_Wp   = (const float*)d_in[21];
    const float* q1_bp   = (const float*)d_in[22];
    const float* q2_W1   = (const float*)d_in[23];
    const float* q2_b1   = (const float*)d_in[24];
    const float* q2_W2   = (const float*)d_in[25];
    const float* q2_b2   = (const float*)d_in[26];
    const float* q2_Wp   = (const float*)d_in[27];
    const float* q2_bp   = (const float*)d_in[28];
    const float* Wout    = (const float*)d_in[29];
    const float* bout    = (const float*)d_in[30];

    float* ws     = (float*)d_ws;
    float* p      = ws;                        // B*32      = 32768 floats
    float* fused  = ws + 32768;                // B*128     = 131072 floats
    float* scores = ws + 32768 + 131072;       // B*L       = 1048576 floats

    float* out = (float*)d_out;

    prep_kernel<<<B_, 128, 0, stream>>>(cats, nums, tgt_ids, cat_emb,
                                        Wnum, bnum, Wq, Wk, Wpool, bpool,
                                        p, fused);
    score_kernel<<<B_ * L_ / 256, 256, 0, stream>>>(seqs, seq_emb, p, scores);
    topk_kernel<<<B_, 256, 0, stream>>>(seqs, seq_emb, scores, Wv, Wo, bo, fused);
    mlp_kernel<<<B_ / R_, 256, 0, stream>>>(fused,
                                            Wmlp, bmlp,
                                            q1_W1, q1_b1, q1_W2, q1_b2, q1_Wp, q1_bp,
                                            q2_W1, q2_b1, q2_W2, q2_b2, q2_Wp, q2_bp,
                                            Wout, bout, out);
}

// Round 3
// 240.490 us; speedup vs baseline: 1.0244x; 1.0244x over previous
//
#include <hip/hip_runtime.h>

#define B_ 1024
#define L_ 1024
#define NCAT_ 20
#define NNUM_ 10
#define E_ 32
#define A_ 128
#define H_ 256
#define TOPK_ 30
#define INV_SQRT_A 0.08838834764831845f

__device__ __forceinline__ void fma4(float4& a, float s, const float4 w) {
    a.x += s * w.x; a.y += s * w.y; a.z += s * w.z; a.w += s * w.w;
}

// ---------------------------------------------------------------------------
// K1: per-row prep (blocks 0..B-1). Block B computes M = Wv @ Wo [E,E].
//   p_b      = Wk @ (tgt_e @ Wq)          [B,32]  (score projection)
//   fused[0:32]  = tgt_e ; fused[64:96] = cat_pool ; fused[96:128] = num_e
// ---------------------------------------------------------------------------
__global__ __launch_bounds__(128) void prep_kernel(
    const int* __restrict__ cats, const float* __restrict__ nums,
    const int* __restrict__ tgt_ids, const float* __restrict__ cat_emb,
    const float* __restrict__ Wnum, const float* __restrict__ bnum,
    const float* __restrict__ Wq, const float* __restrict__ Wk,
    const float* __restrict__ Wv, const float* __restrict__ Wo,
    const float* __restrict__ Wpool, const float* __restrict__ bpool,
    float* __restrict__ p_out, float* __restrict__ fused, float* __restrict__ M)
{
    const int b = blockIdx.x;
    const int t = threadIdx.x;

    if (b == B_) {
        // M[j][e] = sum_a Wv[j*A+a] * Wo[a*E+e]
        for (int o = t; o < E_ * E_; o += 128) {
            int j = o >> 5, e = o & 31;
            float s = 0.f;
#pragma unroll 8
            for (int a = 0; a < A_; ++a) s += Wv[j * A_ + a] * Wo[a * E_ + e];
            M[o] = s;
        }
        return;
    }

    __shared__ float tgt_e[E_];
    __shared__ float qv[A_];
    __shared__ float ce[NCAT_ * E_];
    __shared__ float psum[4][E_];

    if (t < E_) tgt_e[t] = cat_emb[(long)tgt_ids[b] * E_ + t];
    for (int i = t; i < NCAT_ * E_; i += 128) {
        int c = i >> 5, e = i & 31;
        ce[i] = cat_emb[(long)cats[b * NCAT_ + c] * E_ + e];
    }
    __syncthreads();

    float qa = 0.f;
#pragma unroll
    for (int e = 0; e < E_; ++e) qa += tgt_e[e] * Wq[e * A_ + t];
    qv[t] = qa;

    const int j = t & 31, g = t >> 5;
    float cp = 0.f;
    const int i0 = g * 160;
    for (int i = i0; i < i0 + 160; ++i) cp += ce[i] * Wpool[i * E_ + j];
    psum[g][j] = cp;
    __syncthreads();

    if (t < E_) {
        float s = 0.f;
#pragma unroll 8
        for (int a = 0; a < A_; ++a) s += Wk[t * A_ + a] * qv[a];
        p_out[b * E_ + t] = s;

        fused[b * 128 + t] = tgt_e[t];

        float ne = bnum[t];
#pragma unroll
        for (int n = 0; n < NNUM_; ++n) ne += nums[b * NNUM_ + n] * Wnum[n * E_ + t];
        fused[b * 128 + 96 + t] = ne;

        fused[b * 128 + 64 + t] = psum[0][t] + psum[1][t] + psum[2][t] + psum[3][t] + bpool[t];
    }
}

// ---------------------------------------------------------------------------
// K2: fused score + top-30 + softmax + interest.  One block / row.
//   scores in LDS; top-k on wave 0 with register-resident scores (no barriers);
//   interest = (sum_k w_k e_k) @ M + bo  -> fused[32:64]
// ---------------------------------------------------------------------------
__global__ __launch_bounds__(256) void score_topk_kernel(
    const int* __restrict__ seqs, const float* __restrict__ seq_emb,
    const float* __restrict__ p, const float* __restrict__ M,
    const float* __restrict__ bo, float* __restrict__ fused)
{
    const int b = blockIdx.x;
    const int t = threadIdx.x;

    __shared__ float sc[L_];
    __shared__ float ps[E_];
    __shared__ float ebar[E_];
    __shared__ float sw[TOPK_];
    __shared__ int   stok[TOPK_];

    if (t < E_) ps[t] = p[b * E_ + t];
    __syncthreads();

    // ---- scores into LDS (4 tokens / thread)
#pragma unroll
    for (int jj = 0; jj < 4; ++jj) {
        const int l = t + jj * 256;
        const int tok = seqs[b * L_ + l];
        const float4* er = (const float4*)(seq_emb + (long)tok * E_);
        float acc = 0.f;
#pragma unroll
        for (int i = 0; i < 8; ++i) {
            float4 v = er[i];
            acc += v.x * ps[4 * i] + v.y * ps[4 * i + 1] + v.z * ps[4 * i + 2] + v.w * ps[4 * i + 3];
        }
        sc[l] = acc * INV_SQRT_A;
    }
    __syncthreads();

    if (t >= 64) return;   // wave 0 only from here

    const int lane = t;
    float v[16];
#pragma unroll
    for (int j = 0; j < 16; ++j) v[j] = sc[j * 64 + lane];   // token index = j*64+lane

    // lane-local running max
    float lmax = v[0]; int lj = 0;
#pragma unroll
    for (int j = 1; j < 16; ++j) if (v[j] > lmax) { lmax = v[j]; lj = j; }

    float myv = -1e30f; int myl = 0;   // lane k will hold k-th selection
    for (int k = 0; k < TOPK_; ++k) {
        float best = lmax; int bl = lj * 64 + lane;
#pragma unroll
        for (int off = 32; off > 0; off >>= 1) {
            float ov = __shfl_xor(best, off);
            int   ol = __shfl_xor(bl, off);
            if (ov > best || (ov == best && ol < bl)) { best = ov; bl = ol; }
        }
        if (lane == k) { myv = best; myl = bl; }
        if (lane == (bl & 63)) {       // winner lane: zap + recompute local max
            v[bl >> 6] = -1e30f;
            lmax = v[0]; lj = 0;
#pragma unroll
            for (int j = 1; j < 16; ++j) if (v[j] > lmax) { lmax = v[j]; lj = j; }
        }
    }

    // ---- softmax over the 30 selected (whole wave participates in shuffles)
    float m = myv;
#pragma unroll
    for (int off = 32; off > 0; off >>= 1) m = fmaxf(m, __shfl_xor(m, off));
    float e = (lane < TOPK_) ? expf(myv - m) : 0.f;
    float s = e;
#pragma unroll
    for (int off = 32; off > 0; off >>= 1) s += __shfl_xor(s, off);
    if (lane < TOPK_) {
        sw[lane]   = e / s;
        stok[lane] = seqs[b * L_ + myl];
    }

    // ---- ebar[e] = sum_k w_k * seq_emb[tok_k][e]   (lanes 0..31)
    if (lane < E_) {
        float acc = 0.f;
#pragma unroll
        for (int k = 0; k < TOPK_; ++k)
            acc += sw[k] * seq_emb[(long)stok[k] * E_ + lane];
        ebar[lane] = acc;
    }

    // ---- interest = ebar @ M + bo
    if (lane < E_) {
        float acc = bo[lane];
#pragma unroll
        for (int j = 0; j < E_; ++j) acc += ebar[j] * M[j * E_ + lane];
        fused[b * 128 + 32 + lane] = acc;
    }
}

// ---------------------------------------------------------------------------
// K3: MLP chain, v2. 256 blocks x 512 threads, RM=4 rows/block.
//   thread -> 4 consecutive cols (float4 weight loads), i-dim split over the
//   8 waves, partial sums combined through LDS.
// ---------------------------------------------------------------------------
#define RM 4
__global__ __launch_bounds__(512) void mlp_kernel(
    const float* __restrict__ fused,
    const float* __restrict__ Wmlp, const float* __restrict__ bmlp,
    const float* __restrict__ W11, const float* __restrict__ b11,
    const float* __restrict__ W12, const float* __restrict__ b12,
    const float* __restrict__ W1p, const float* __restrict__ b1p,
    const float* __restrict__ W21, const float* __restrict__ b21,
    const float* __restrict__ W22, const float* __restrict__ b22,
    const float* __restrict__ W2p, const float* __restrict__ b2p,
    const float* __restrict__ Wout, const float* __restrict__ bout,
    float* __restrict__ out)
{
    const int b0 = blockIdx.x * RM;
    const int tid = threadIdx.x;
    const int cg = tid & 63;          // col group: cols 4cg..4cg+3
    const int iseg = tid >> 6;        // 0..7 (== wave id)
    const int c0 = cg * 4;

    __shared__ float xs[RM][128];
    __shared__ float hs[RM][H_];
    __shared__ float ts[RM][H_];
    __shared__ float part[2][8][RM][H_];   // 64 KB
    __shared__ float red[8];

    for (int i = tid; i < RM * 128; i += 512) xs[i >> 7][i & 127] = fused[b0 * 128 + i];
    __syncthreads();

    // ---- stage 1: hs = relu(xs @ Wmlp + bmlp), K = 128 (16 i's per wave)
    {
        float4 acc[RM];
#pragma unroll
        for (int r = 0; r < RM; ++r) acc[r] = make_float4(0.f, 0.f, 0.f, 0.f);
        const int i0 = iseg * 16;
#pragma unroll
        for (int iq = 0; iq < 4; ++iq) {
            const int i = i0 + iq * 4;
            float4 w[4], xv[RM];
#pragma unroll
            for (int u = 0; u < 4; ++u) w[u] = *(const float4*)(Wmlp + (i + u) * H_ + c0);
#pragma unroll
            for (int r = 0; r < RM; ++r) xv[r] = *(const float4*)(&xs[r][i]);
#pragma unroll
            for (int r = 0; r < RM; ++r) {
                fma4(acc[r], xv[r].x, w[0]); fma4(acc[r], xv[r].y, w[1]);
                fma4(acc[r], xv[r].z, w[2]); fma4(acc[r], xv[r].w, w[3]);
            }
        }
#pragma unroll
        for (int r = 0; r < RM; ++r) *(float4*)&part[0][iseg][r][c0] = acc[r];
    }
    __syncthreads();
    for (int o = tid; o < RM * H_; o += 512) {
        const int r = o >> 8, c = o & 255;
        float s = bmlp[c];
#pragma unroll
        for (int sg = 0; sg < 8; ++sg) s += part[0][sg][r][c];
        hs[r][c] = fmaxf(s, 0.f);
    }
    __syncthreads();

    // ---- two qnn blocks
    const float* W1s[2] = { W11, W21 }; const float* b1s[2] = { b11, b21 };
    const float* W2s[2] = { W12, W22 }; const float* b2s[2] = { b12, b22 };
    const float* Wps[2] = { W1p, W2p }; const float* bps[2] = { b1p, b2p };

    for (int q = 0; q < 2; ++q) {
        const float* __restrict__ W1 = W1s[q];
        const float* __restrict__ W2 = W2s[q];
        const float* __restrict__ Wp = Wps[q];

        // dual GEMV: t1 = hs@W1, t2 = hs@W2 (K=256, 32 i's per wave)
        {
            float4 a1[RM], a2[RM];
#pragma unroll
            for (int r = 0; r < RM; ++r) {
                a1[r] = make_float4(0.f, 0.f, 0.f, 0.f);
                a2[r] = make_float4(0.f, 0.f, 0.f, 0.f);
            }
            const int i0 = iseg * 32;
#pragma unroll 2
            for (int iq = 0; iq < 8; ++iq) {
                const int i = i0 + iq * 4;
                float4 w1[4], w2[4], hv[RM];
#pragma unroll
                for (int u = 0; u < 4; ++u) {
                    w1[u] = *(const float4*)(W1 + (i + u) * H_ + c0);
                    w2[u] = *(const float4*)(W2 + (i + u) * H_ + c0);
                }
#pragma unroll
                for (int r = 0; r < RM; ++r) hv[r] = *(const float4*)(&hs[r][i]);
#pragma unroll
                for (int r = 0; r < RM; ++r) {
                    fma4(a1[r], hv[r].x, w1[0]); fma4(a1[r], hv[r].y, w1[1]);
                    fma4(a1[r], hv[r].z, w1[2]); fma4(a1[r], hv[r].w, w1[3]);
                    fma4(a2[r], hv[r].x, w2[0]); fma4(a2[r], hv[r].y, w2[1]);
                    fma4(a2[r], hv[r].z, w2[2]); fma4(a2[r], hv[r].w, w2[3]);
                }
            }
#pragma unroll
            for (int r = 0; r < RM; ++r) {
                *(float4*)&part[0][iseg][r][c0] = a1[r];
                *(float4*)&part[1][iseg][r][c0] = a2[r];
            }
        }
        __syncthreads();
        {
            const float* b1 = b1s[q]; const float* b2 = b2s[q];
            for (int o = tid; o < RM * H_; o += 512) {
                const int r = o >> 8, c = o & 255;
                float t1 = b1[c], t2 = b2[c];
#pragma unroll
                for (int sg = 0; sg < 8; ++sg) { t1 += part[0][sg][r][c]; t2 += part[1][sg][r][c]; }
                ts[r][c] = t1 * t2;
            }
        }
        __syncthreads();

        // projection: hs += ts @ Wp + bp
        {
            float4 ap[RM];
#pragma unroll
            for (int r = 0; r < RM; ++r) ap[r] = make_float4(0.f, 0.f, 0.f, 0.f);
            const int i0 = iseg * 32;
#pragma unroll 2
            for (int iq = 0; iq < 8; ++iq) {
                const int i = i0 + iq * 4;
                float4 w[4], tv[RM];
#pragma unroll
                for (int u = 0; u < 4; ++u) w[u] = *(const float4*)(Wp + (i + u) * H_ + c0);
#pragma unroll
                for (int r = 0; r < RM; ++r) tv[r] = *(const float4*)(&ts[r][i]);
#pragma unroll
                for (int r = 0; r < RM; ++r) {
                    fma4(ap[r], tv[r].x, w[0]); fma4(ap[r], tv[r].y, w[1]);
                    fma4(ap[r], tv[r].z, w[2]); fma4(ap[r], tv[r].w, w[3]);
                }
            }
#pragma unroll
            for (int r = 0; r < RM; ++r) *(float4*)&part[0][iseg][r][c0] = ap[r];
        }
        __syncthreads();
        {
            const float* bp = bps[q];
            for (int o = tid; o < RM * H_; o += 512) {
                const int r = o >> 8, c = o & 255;
                float s = bp[c];
#pragma unroll
                for (int sg = 0; sg < 8; ++sg) s += part[0][sg][r][c];
                hs[r][c] += s;
            }
        }
        __syncthreads();
    }

    // ---- out[r] = hs[r] . Wout + bout
    // 128 threads per row, each thread covers cols jj and jj+128 (256 total).
    {
        const int r = tid >> 7, jj = tid & 127;
        float pv = hs[r][jj] * Wout[jj] + hs[r][jj + 128] * Wout[jj + 128];
        float sum = pv;
#pragma unroll
        for (int off = 32; off > 0; off >>= 1) sum += __shfl_down(sum, off);
        if ((tid & 63) == 0) red[tid >> 6] = sum;
        __syncthreads();
        if (tid < RM) out[b0 + tid] = red[2 * tid] + red[2 * tid + 1] + bout[0];
    }
}

// ---------------------------------------------------------------------------
extern "C" void kernel_launch(void* const* d_in, const int* in_sizes, int n_in,
                              void* d_out, int out_size, void* d_ws, size_t ws_size,
                              hipStream_t stream) {
    const int*   cats    = (const int*)d_in[0];
    const float* nums    = (const float*)d_in[1];
    const int*   seqs    = (const int*)d_in[2];
    const int*   tgt_ids = (const int*)d_in[3];
    const float* cat_emb = (const float*)d_in[4];
    const float* seq_emb = (const float*)d_in[5];
    const float* Wnum    = (const float*)d_in[6];
    const float* bnum    = (const float*)d_in[7];
    const float* Wq      = (const float*)d_in[8];
    const float* Wk      = (const float*)d_in[9];
    const float* Wv      = (const float*)d_in[10];
    const float* Wo      = (const float*)d_in[11];
    const float* bo      = (const float*)d_in[12];
    const float* Wpool   = (const float*)d_in[13];
    const float* bpool   = (const float*)d_in[14];
    const float* Wmlp    = (const float*)d_in[15];
    const float* bmlp    = (const float*)d_in[16];
    const float* q1_W1   = (const float*)d_in[17];
    const float* q1_b1   = (const float*)d_in[18];
    const float* q1_W2   = (const float*)d_in[19];
    const float* q1_b2   = (const float*)d_in[20];
    const float* q1_Wp   = (const float*)d_in[21];
    const float* q1_bp   = (const float*)d_in[22];
    const float* q2_W1   = (const float*)d_in[23];
    const float* q2_b1   = (const float*)d_in[24];
    const float* q2_W2   = (const float*)d_in[25];
    const float* q2_b2   = (const float*)d_in[26];
    const float* q2_Wp   = (const float*)d_in[27];
    const float* q2_bp   = (const float*)d_in[28];
    const float* Wout    = (const float*)d_in[29];
    const float* bout    = (const float*)d_in[30];

    float* ws    = (float*)d_ws;
    float* p     = ws;                       // B*32
    float* fused = ws + 32768;               // B*128
    float* M     = ws + 32768 + 131072;      // 32*32

    float* out = (float*)d_out;

    prep_kernel<<<B_ + 1, 128, 0, stream>>>(cats, nums, tgt_ids, cat_emb,
                                            Wnum, bnum, Wq, Wk, Wv, Wo, Wpool, bpool,
                                            p, fused, M);
    score_topk_kernel<<<B_, 256, 0, stream>>>(seqs, seq_emb, p, M, bo, fused);
    mlp_kernel<<<B_ / RM, 512, 0, stream>>>(fused,
                                            Wmlp, bmlp,
                                            q1_W1, q1_b1, q1_W2, q1_b2, q1_Wp, q1_bp,
                                            q2_W1, q2_b1, q2_W2, q2_b2, q2_Wp, q2_bp,
                                            Wout, bout, out);
}

// Round 4
// 229.020 us; speedup vs baseline: 1.0757x; 1.0501x over previous
//
#include <hip/hip_runtime.h>
#include <hip/hip_fp16.h>

#define B_ 1024
#define L_ 1024
#define NCAT_ 20
#define NNUM_ 10
#define E_ 32
#define A_ 128
#define H_ 256
#define TOPK_ 30
#define INV_SQRT_A 0.08838834764831845f

__device__ __forceinline__ void fma4(float4& a, float s, const float4 w) {
    a.x += s * w.x; a.y += s * w.y; a.z += s * w.z; a.w += s * w.w;
}

// load 4 consecutive fp16 as float4 (8 B load)
__device__ __forceinline__ float4 ldh4(const __half* p) {
    float2 rw = *(const float2*)p;
    const __half2* h = (const __half2*)&rw;
    float2 a = __half22float2(h[0]);
    float2 b = __half22float2(h[1]);
    return make_float4(a.x, a.y, b.x, b.y);
}
// load 4 packed half2(w1,w2) as two float4 (16 B load)
__device__ __forceinline__ void ldh24(const __half2* p, float4& w1, float4& w2) {
    float4 rw = *(const float4*)p;
    const __half2* h = (const __half2*)&rw;
    float2 f0 = __half22float2(h[0]), f1 = __half22float2(h[1]);
    float2 f2 = __half22float2(h[2]), f3 = __half22float2(h[3]);
    w1 = make_float4(f0.x, f1.x, f2.x, f3.x);
    w2 = make_float4(f0.y, f1.y, f2.y, f3.y);
}

// ---------------------------------------------------------------------------
// K0a: M = Wv@Wo [E,E]; N = Wq@Wk^T [E,E].  One block.
// ---------------------------------------------------------------------------
__global__ __launch_bounds__(256) void const_kernel(
    const float* __restrict__ Wq, const float* __restrict__ Wk,
    const float* __restrict__ Wv, const float* __restrict__ Wo,
    float* __restrict__ M, float* __restrict__ N)
{
    const int t = threadIdx.x;
    for (int o = t; o < E_ * E_; o += 256) {
        const int j = o >> 5, e = o & 31;
        float sm = 0.f, sn = 0.f;
#pragma unroll 8
        for (int a = 0; a < A_; ++a) {
            sm += Wv[j * A_ + a] * Wo[a * E_ + e];   // M[j][e]
            sn += Wq[j * A_ + a] * Wk[e * A_ + a];   // N[j][e] = sum_a Wq[j,a]Wk[e,a]
        }
        M[o] = sm; N[o] = sn;
    }
}

// ---------------------------------------------------------------------------
// K0b: fp16 conversions into workspace.
//   seq_h2   : seq_emb as half2               (800016 half2)
//   Wmlp_h2  : Wmlp fp16                      (16384 half2)
//   W12_q    : half2(W1[i][c], W2[i][c])      (65536 half2 each qnn)
//   Wp_h2    : Wp fp16                        (16384 half2 each qnn)
// ---------------------------------------------------------------------------
#define SEQH2 800016
__global__ void convert_kernel(
    const float* __restrict__ seq_emb, const float* __restrict__ Wmlp,
    const float* __restrict__ q1W1, const float* __restrict__ q1W2,
    const float* __restrict__ q2W1, const float* __restrict__ q2W2,
    const float* __restrict__ q1Wp, const float* __restrict__ q2Wp,
    __half2* __restrict__ seq_h2, __half2* __restrict__ Wmlp_h2,
    __half2* __restrict__ W12_1, __half2* __restrict__ W12_2,
    __half2* __restrict__ Wp1_h2, __half2* __restrict__ Wp2_h2)
{
    const int i0 = blockIdx.x * blockDim.x + threadIdx.x;
    const int st = gridDim.x * blockDim.x;
    for (int x = i0; x < SEQH2; x += st) {
        float2 v = ((const float2*)seq_emb)[x];
        seq_h2[x] = __float22half2_rn(v);
    }
    for (int x = i0; x < 16384; x += st) {
        float2 v = ((const float2*)Wmlp)[x];
        Wmlp_h2[x] = __float22half2_rn(v);
    }
    for (int x = i0; x < 65536; x += st)
        W12_1[x] = __float22half2_rn(make_float2(q1W1[x], q1W2[x]));
    for (int x = i0; x < 65536; x += st)
        W12_2[x] = __float22half2_rn(make_float2(q2W1[x], q2W2[x]));
    for (int x = i0; x < 16384; x += st) {
        float2 v = ((const float2*)q1Wp)[x];
        Wp1_h2[x] = __float22half2_rn(v);
    }
    for (int x = i0; x < 16384; x += st) {
        float2 v = ((const float2*)q2Wp)[x];
        Wp2_h2[x] = __float22half2_rn(v);
    }
}

// ---------------------------------------------------------------------------
// K1: prep, 256 blocks x 4 rows.  p = tgt_e @ N; fused[0:32]=tgt_e;
//     fused[64:96]=cat_pool; fused[96:128]=num_e.
// ---------------------------------------------------------------------------
__global__ __launch_bounds__(256) void prep_kernel(
    const int* __restrict__ cats, const float* __restrict__ nums,
    const int* __restrict__ tgt_ids, const float* __restrict__ cat_emb,
    const float* __restrict__ Wnum, const float* __restrict__ bnum,
    const float* __restrict__ Wpool, const float* __restrict__ bpool,
    const float* __restrict__ N,
    float* __restrict__ p_out, float* __restrict__ fused)
{
    const int r0 = blockIdx.x * 4;
    const int t = threadIdx.x;

    __shared__ float ce[4][NCAT_ * E_];   // 10 KB
    __shared__ float tg[4][E_];
    __shared__ float nm[4][NNUM_];
    __shared__ float part[8][4][E_];      // 4 KB

    // gather 80 cat rows (640 float4) + 4 tgt rows + nums
    for (int idx = t; idx < 640; idx += 256) {
        const int q = idx >> 3, f4 = idx & 7;
        const int row = q / 20, cat = q % 20;
        const int tok = cats[(r0 + row) * NCAT_ + cat];
        ((float4*)&ce[row][cat * 32])[f4] =
            ((const float4*)(cat_emb + (size_t)tok * 32))[f4];
    }
    if (t < 32) {
        const int row = t >> 3, f4 = t & 7;
        const int tok = tgt_ids[r0 + row];
        ((float4*)&tg[row][0])[f4] =
            ((const float4*)(cat_emb + (size_t)tok * 32))[f4];
    }
    if (t >= 64 && t < 104) {
        const int x = t - 64;
        nm[x / 10][x % 10] = nums[(r0 + x / 10) * NNUM_ + x % 10];
    }
    __syncthreads();

    // cat_pool partials: t = iseg(8) x row(4) x cg(8)
    {
        const int iseg = t >> 5;
        const int row = (t >> 3) & 3;
        const int c0 = (t & 7) * 4;
        float4 acc = make_float4(0.f, 0.f, 0.f, 0.f);
        const int i0 = iseg * 80;
        for (int i = i0; i < i0 + 80; ++i) {
            float4 w = *(const float4*)(Wpool + i * 32 + c0);
            fma4(acc, ce[row][i], w);
        }
        *(float4*)&part[iseg][row][c0] = acc;
    }
    __syncthreads();

    if (t < 128) {
        const int row = t >> 5, c = t & 31;
        const int b = r0 + row;
        float s = bpool[c];
#pragma unroll
        for (int g = 0; g < 8; ++g) s += part[g][row][c];
        fused[b * 128 + 64 + c] = s;
        fused[b * 128 + c] = tg[row][c];

        float ne = bnum[c];
#pragma unroll
        for (int n = 0; n < NNUM_; ++n) ne += nm[row][n] * Wnum[n * 32 + c];
        fused[b * 128 + 96 + c] = ne;

        float pv = 0.f;
#pragma unroll
        for (int e = 0; e < E_; ++e) pv += tg[row][e] * N[e * 32 + c];
        p_out[b * 32 + c] = pv;
    }
}

// ---------------------------------------------------------------------------
// K2: fused score (fp16 gathers) + top-30 + softmax + interest.  1 block/row.
// ---------------------------------------------------------------------------
__global__ __launch_bounds__(256) void score_topk_kernel(
    const int* __restrict__ seqs, const __half* __restrict__ seq_h,
    const float* __restrict__ seq_emb,
    const float* __restrict__ p, const float* __restrict__ M,
    const float* __restrict__ bo, float* __restrict__ fused)
{
    const int b = blockIdx.x;
    const int t = threadIdx.x;

    __shared__ float sc[L_];
    __shared__ float ps[E_];
    __shared__ float sw[TOPK_];
    __shared__ int   stok[TOPK_];

    if (t < E_) ps[t] = p[b * E_ + t];
    __syncthreads();

    // ---- scores: 4 tokens / thread, all 16 row-loads buffered in registers
    {
        int toks[4];
#pragma unroll
        for (int jj = 0; jj < 4; ++jj) toks[jj] = seqs[b * L_ + t + jj * 256];
        float4 buf[4][4];
#pragma unroll
        for (int jj = 0; jj < 4; ++jj) {
            const float4* er = (const float4*)(seq_h + (size_t)toks[jj] * 32);
#pragma unroll
            for (int i = 0; i < 4; ++i) buf[jj][i] = er[i];
        }
#pragma unroll
        for (int jj = 0; jj < 4; ++jj) {
            float acc = 0.f;
#pragma unroll
            for (int i = 0; i < 4; ++i) {
                const __half2* h = (const __half2*)&buf[jj][i];
#pragma unroll
                for (int u = 0; u < 4; ++u) {
                    float2 f = __half22float2(h[u]);
                    acc += f.x * ps[i * 8 + 2 * u] + f.y * ps[i * 8 + 2 * u + 1];
                }
            }
            sc[t + jj * 256] = acc * INV_SQRT_A;
        }
    }
    __syncthreads();

    if (t >= 64) return;   // wave 0 only from here

    const int lane = t;
    float v[16];
#pragma unroll
    for (int j = 0; j < 16; ++j) v[j] = sc[j * 64 + lane];

    float lmax = v[0]; int lj = 0;
#pragma unroll
    for (int j = 1; j < 16; ++j) if (v[j] > lmax) { lmax = v[j]; lj = j; }

    float myv = -1e30f; int myl = 0;
    for (int k = 0; k < TOPK_; ++k) {
        float best = lmax; int bl = lj * 64 + lane;
#pragma unroll
        for (int off = 32; off > 0; off >>= 1) {
            float ov = __shfl_xor(best, off);
            int   ol = __shfl_xor(bl, off);
            if (ov > best || (ov == best && ol < bl)) { best = ov; bl = ol; }
        }
        if (lane == k) { myv = best; myl = bl; }
        if (lane == (bl & 63)) {
            v[bl >> 6] = -1e30f;
            lmax = v[0]; lj = 0;
#pragma unroll
            for (int j = 1; j < 16; ++j) if (v[j] > lmax) { lmax = v[j]; lj = j; }
        }
    }

    // softmax over top-30
    float m = myv;
#pragma unroll
    for (int off = 32; off > 0; off >>= 1) m = fmaxf(m, __shfl_xor(m, off));
    float e = (lane < TOPK_) ? expf(myv - m) : 0.f;
    float s = e;
#pragma unroll
    for (int off = 32; off > 0; off >>= 1) s += __shfl_xor(s, off);
    if (lane < TOPK_) {
        sw[lane]   = e / s;
        stok[lane] = seqs[b * L_ + myl];
    }

    // ebar from fp32 table (exact), then interest = ebar @ M + bo
    if (lane < E_) {
        float acc = 0.f;
#pragma unroll
        for (int k = 0; k < TOPK_; ++k)
            acc += sw[k] * seq_emb[(size_t)stok[k] * 32 + lane];
        // acc = ebar[lane]; need full ebar -> via LDS
        sc[lane] = acc;
    }
    if (lane < E_) {
        float acc = bo[lane];
#pragma unroll
        for (int j = 0; j < E_; ++j) acc += sc[j] * M[j * E_ + lane];
        fused[b * 128 + 32 + lane] = acc;
    }
}

// ---------------------------------------------------------------------------
// K3: MLP chain, fp16 packed weights. 256 blocks x 512 threads, RM=4.
// ---------------------------------------------------------------------------
#define RM 4
__global__ __launch_bounds__(512) void mlp_kernel(
    const float* __restrict__ fused,
    const __half* __restrict__ Wmlp_h, const float* __restrict__ bmlp,
    const __half2* __restrict__ W12_1, const float* __restrict__ b11,
    const float* __restrict__ b12, const __half* __restrict__ Wp1_h,
    const float* __restrict__ b1p,
    const __half2* __restrict__ W12_2, const float* __restrict__ b21,
    const float* __restrict__ b22, const __half* __restrict__ Wp2_h,
    const float* __restrict__ b2p,
    const float* __restrict__ Wout, const float* __restrict__ bout,
    float* __restrict__ out)
{
    const int b0 = blockIdx.x * RM;
    const int tid = threadIdx.x;
    const int cg = tid & 63;          // 64 col groups of 4
    const int iseg = tid >> 6;        // 8 i-segments (wave id)
    const int c0 = cg * 4;

    __shared__ float xs[RM][128];
    __shared__ float hs[RM][H_];
    __shared__ float ts[RM][H_];
    __shared__ float part[2][8][RM][H_];   // 64 KB
    __shared__ float red[8];

    for (int i = tid; i < RM * 128; i += 512) xs[i >> 7][i & 127] = fused[b0 * 128 + i];
    __syncthreads();

    // ---- stage 1: hs = relu(xs @ Wmlp + bmlp), K=128
    {
        float4 acc[RM];
#pragma unroll
        for (int r = 0; r < RM; ++r) acc[r] = make_float4(0.f, 0.f, 0.f, 0.f);
        const int i0 = iseg * 16;
#pragma unroll
        for (int iq = 0; iq < 4; ++iq) {
            const int i = i0 + iq * 4;
            float4 w[4], xv[RM];
#pragma unroll
            for (int u = 0; u < 4; ++u) w[u] = ldh4(Wmlp_h + (i + u) * H_ + c0);
#pragma unroll
            for (int r = 0; r < RM; ++r) xv[r] = *(const float4*)(&xs[r][i]);
#pragma unroll
            for (int r = 0; r < RM; ++r) {
                fma4(acc[r], xv[r].x, w[0]); fma4(acc[r], xv[r].y, w[1]);
                fma4(acc[r], xv[r].z, w[2]); fma4(acc[r], xv[r].w, w[3]);
            }
        }
#pragma unroll
        for (int r = 0; r < RM; ++r) *(float4*)&part[0][iseg][r][c0] = acc[r];
    }
    __syncthreads();
    for (int o = tid; o < RM * H_; o += 512) {
        const int r = o >> 8, c = o & 255;
        float s = bmlp[c];
#pragma unroll
        for (int sg = 0; sg < 8; ++sg) s += part[0][sg][r][c];
        hs[r][c] = fmaxf(s, 0.f);
    }
    __syncthreads();

    // ---- two qnn blocks
    const __half2* W12s[2] = { W12_1, W12_2 };
    const float* b1s[2] = { b11, b21 }; const float* b2s[2] = { b12, b22 };
    const __half* Wps[2] = { Wp1_h, Wp2_h }; const float* bps[2] = { b1p, b2p };

    for (int q = 0; q < 2; ++q) {
        const __half2* __restrict__ W12 = W12s[q];
        const __half*  __restrict__ Wp  = Wps[q];

        // dual GEMV via packed half2 weights
        {
            float4 a1[RM], a2[RM];
#pragma unroll
            for (int r = 0; r < RM; ++r) {
                a1[r] = make_float4(0.f, 0.f, 0.f, 0.f);
                a2[r] = make_float4(0.f, 0.f, 0.f, 0.f);
            }
            const int i0 = iseg * 32;
#pragma unroll 2
            for (int iq = 0; iq < 8; ++iq) {
                const int i = i0 + iq * 4;
                float4 w1[4], w2[4], hv[RM];
#pragma unroll
                for (int u = 0; u < 4; ++u) ldh24(W12 + (i + u) * H_ + c0, w1[u], w2[u]);
#pragma unroll
                for (int r = 0; r < RM; ++r) hv[r] = *(const float4*)(&hs[r][i]);
#pragma unroll
                for (int r = 0; r < RM; ++r) {
                    fma4(a1[r], hv[r].x, w1[0]); fma4(a1[r], hv[r].y, w1[1]);
                    fma4(a1[r], hv[r].z, w1[2]); fma4(a1[r], hv[r].w, w1[3]);
                    fma4(a2[r], hv[r].x, w2[0]); fma4(a2[r], hv[r].y, w2[1]);
                    fma4(a2[r], hv[r].z, w2[2]); fma4(a2[r], hv[r].w, w2[3]);
                }
            }
#pragma unroll
            for (int r = 0; r < RM; ++r) {
                *(float4*)&part[0][iseg][r][c0] = a1[r];
                *(float4*)&part[1][iseg][r][c0] = a2[r];
            }
        }
        __syncthreads();
        {
            const float* b1 = b1s[q]; const float* b2 = b2s[q];
            for (int o = tid; o < RM * H_; o += 512) {
                const int r = o >> 8, c = o & 255;
                float t1 = b1[c], t2 = b2[c];
#pragma unroll
                for (int sg = 0; sg < 8; ++sg) { t1 += part[0][sg][r][c]; t2 += part[1][sg][r][c]; }
                ts[r][c] = t1 * t2;
            }
        }
        __syncthreads();

        // projection: hs += ts @ Wp + bp
        {
            float4 ap[RM];
#pragma unroll
            for (int r = 0; r < RM; ++r) ap[r] = make_float4(0.f, 0.f, 0.f, 0.f);
            const int i0 = iseg * 32;
#pragma unroll 2
            for (int iq = 0; iq < 8; ++iq) {
                const int i = i0 + iq * 4;
                float4 w[4], tv[RM];
#pragma unroll
                for (int u = 0; u < 4; ++u) w[u] = ldh4(Wp + (i + u) * H_ + c0);
#pragma unroll
                for (int r = 0; r < RM; ++r) tv[r] = *(const float4*)(&ts[r][i]);
#pragma unroll
                for (int r = 0; r < RM; ++r) {
                    fma4(ap[r], tv[r].x, w[0]); fma4(ap[r], tv[r].y, w[1]);
                    fma4(ap[r], tv[r].z, w[2]); fma4(ap[r], tv[r].w, w[3]);
                }
            }
#pragma unroll
            for (int r = 0; r < RM; ++r) *(float4*)&part[0][iseg][r][c0] = ap[r];
        }
        __syncthreads();
        {
            const float* bp = bps[q];
            for (int o = tid; o < RM * H_; o += 512) {
                const int r = o >> 8, c = o & 255;
                float s = bp[c];
#pragma unroll
                for (int sg = 0; sg < 8; ++sg) s += part[0][sg][r][c];
                hs[r][c] += s;
            }
        }
        __syncthreads();
    }

    // ---- out[r] = hs[r].Wout + bout  (128 thr/row, 2 cols each)
    {
        const int r = tid >> 7, jj = tid & 127;
        float sum = hs[r][jj] * Wout[jj] + hs[r][jj + 128] * Wout[jj + 128];
#pragma unroll
        for (int off = 32; off > 0; off >>= 1) sum += __shfl_down(sum, off);
        if ((tid & 63) == 0) red[tid >> 6] = sum;
        __syncthreads();
        if (tid < RM) out[b0 + tid] = red[2 * tid] + red[2 * tid + 1] + bout[0];
    }
}

// ---------------------------------------------------------------------------
extern "C" void kernel_launch(void* const* d_in, const int* in_sizes, int n_in,
                              void* d_out, int out_size, void* d_ws, size_t ws_size,
                              hipStream_t stream) {
    const int*   cats    = (const int*)d_in[0];
    const float* nums    = (const float*)d_in[1];
    const int*   seqs    = (const int*)d_in[2];
    const int*   tgt_ids = (const int*)d_in[3];
    const float* cat_emb = (const float*)d_in[4];
    const float* seq_emb = (const float*)d_in[5];
    const float* Wnum    = (const float*)d_in[6];
    const float* bnum    = (const float*)d_in[7];
    const float* Wq      = (const float*)d_in[8];
    const float* Wk      = (const float*)d_in[9];
    const float* Wv      = (const float*)d_in[10];
    const float* Wo      = (const float*)d_in[11];
    const float* bo      = (const float*)d_in[12];
    const float* Wpool   = (const float*)d_in[13];
    const float* bpool   = (const float*)d_in[14];
    const float* Wmlp    = (const float*)d_in[15];
    const float* bmlp    = (const float*)d_in[16];
    const float* q1_W1   = (const float*)d_in[17];
    const float* q1_b1   = (const float*)d_in[18];
    const float* q1_W2   = (const float*)d_in[19];
    const float* q1_b2   = (const float*)d_in[20];
    const float* q1_Wp   = (const float*)d_in[21];
    const float* q1_bp   = (const float*)d_in[22];
    const float* q2_W1   = (const float*)d_in[23];
    const float* q2_b1   = (const float*)d_in[24];
    const float* q2_W2   = (const float*)d_in[25];
    const float* q2_b2   = (const float*)d_in[26];
    const float* q2_Wp   = (const float*)d_in[27];
    const float* q2_bp   = (const float*)d_in[28];
    const float* Wout    = (const float*)d_in[29];
    const float* bout    = (const float*)d_in[30];

    float* ws = (float*)d_ws;
    float*   p       = ws;                    // 32768
    float*   fused   = ws + 32768;            // 131072
    float*   M       = ws + 163840;           // 1024
    float*   N       = ws + 164864;           // 1024
    __half2* seq_h2  = (__half2*)(ws + 165888);   // 800016 half2 (pad 800064 fl)
    __half2* Wmlp_h2 = (__half2*)(ws + 965952);   // 16384 fl
    __half2* W12_1   = (__half2*)(ws + 982336);   // 65536 fl
    __half2* W12_2   = (__half2*)(ws + 1047872);  // 65536 fl
    __half2* Wp1_h2  = (__half2*)(ws + 1113408);  // 16384 fl
    __half2* Wp2_h2  = (__half2*)(ws + 1129792);  // 16384 fl -> end 1146176 fl

    float* out = (float*)d_out;

    const_kernel<<<1, 256, 0, stream>>>(Wq, Wk, Wv, Wo, M, N);
    convert_kernel<<<1024, 256, 0, stream>>>(seq_emb, Wmlp,
                                             q1_W1, q1_W2, q2_W1, q2_W2,
                                             q1_Wp, q2_Wp,
                                             seq_h2, Wmlp_h2, W12_1, W12_2,
                                             Wp1_h2, Wp2_h2);
    prep_kernel<<<B_ / 4, 256, 0, stream>>>(cats, nums, tgt_ids, cat_emb,
                                            Wnum, bnum, Wpool, bpool, N,
                                            p, fused);
    score_topk_kernel<<<B_, 256, 0, stream>>>(seqs, (const __half*)seq_h2, seq_emb,
                                              p, M, bo, fused);
    mlp_kernel<<<B_ / RM, 512, 0, stream>>>(fused,
                                            (const __half*)Wmlp_h2, bmlp,
                                            W12_1, q1_b1, q1_b2, (const __half*)Wp1_h2, q1_bp,
                                            W12_2, q2_b1, q2_b2, (const __half*)Wp2_h2, q2_bp,
                                            Wout, bout, out);
}

// Round 7
// 195.037 us; speedup vs baseline: 1.2631x; 1.1742x over previous
//
#include <hip/hip_runtime.h>
#include <hip/hip_fp16.h>

#define B_ 1024
#define L_ 1024
#define NCAT_ 20
#define NNUM_ 10
#define E_ 32
#define A_ 128
#define H_ 256
#define TOPK_ 30
#define INV_SQRT_A 0.08838834764831845f

__device__ __forceinline__ void fma4(float4& a, float s, const float4 w) {
    a.x += s * w.x; a.y += s * w.y; a.z += s * w.z; a.w += s * w.w;
}
__device__ __forceinline__ float4 ldh4(const __half* p) {
    float2 rw = *(const float2*)p;
    const __half2* h = (const __half2*)&rw;
    float2 a = __half22float2(h[0]);
    float2 b = __half22float2(h[1]);
    return make_float4(a.x, a.y, b.x, b.y);
}
__device__ __forceinline__ void ldh24(const __half2* p, float4& w1, float4& w2) {
    float4 rw = *(const float4*)p;
    const __half2* h = (const __half2*)&rw;
    float2 f0 = __half22float2(h[0]), f1 = __half22float2(h[1]);
    float2 f2 = __half22float2(h[2]), f3 = __half22float2(h[3]);
    w1 = make_float4(f0.x, f1.x, f2.x, f3.x);
    w2 = make_float4(f0.y, f1.y, f2.y, f3.y);
}

// ---------------------------------------------------------------------------
// K1: multi-role fused kernel (grid 1356 x 256):
//   blocks [0,256)     : prep, 4 rows each (self-contained q,p from Wq,Wk)
//   blocks [256,1280)  : seq_emb -> fp16 convert
//   blocks [1280,1284) : M = Wv@Wo
//   blocks [1284,1348) : pack half2(W1,W2) for both qnn
//   blocks [1348,1356) : Wmlp, Wp1, Wp2 -> fp16
// ---------------------------------------------------------------------------
#define K1_GRID 1356
__global__ __launch_bounds__(256) void fused_prep_kernel(
    const int* __restrict__ cats, const float* __restrict__ nums,
    const int* __restrict__ tgt_ids, const float* __restrict__ cat_emb,
    const float* __restrict__ Wnum, const float* __restrict__ bnum,
    const float* __restrict__ Wq, const float* __restrict__ Wk,
    const float* __restrict__ Wv, const float* __restrict__ Wo,
    const float* __restrict__ Wpool, const float* __restrict__ bpool,
    const float* __restrict__ seq_emb, const float* __restrict__ Wmlp,
    const float* __restrict__ q1W1, const float* __restrict__ q1W2,
    const float* __restrict__ q2W1, const float* __restrict__ q2W2,
    const float* __restrict__ q1Wp, const float* __restrict__ q2Wp,
    float* __restrict__ p_out, float* __restrict__ fused, float* __restrict__ M,
    __half2* __restrict__ seq_h2, __half2* __restrict__ Wmlp_h2,
    __half2* __restrict__ W12_1, __half2* __restrict__ W12_2,
    __half2* __restrict__ Wp1_h2, __half2* __restrict__ Wp2_h2)
{
    const int blk = blockIdx.x;
    const int t = threadIdx.x;

    if (blk < 256) {
        // ---------------- prep: rows r0..r0+3 ----------------
        __shared__ float ce[4][NCAT_ * E_];   // 10 KB
        __shared__ float tg[4][E_];
        __shared__ float nm[4][NNUM_];
        __shared__ float qs[4][A_];           // 2 KB
        __shared__ float part[8][4][E_];      // 4 KB
        const int r0 = blk * 4;

        for (int idx = t; idx < 640; idx += 256) {
            const int q = idx >> 3, f4 = idx & 7;
            const int row = q / 20, cat = q % 20;
            const int tok = cats[(r0 + row) * NCAT_ + cat];
            ((float4*)&ce[row][cat * 32])[f4] =
                ((const float4*)(cat_emb + (size_t)tok * 32))[f4];
        }
        if (t < 32) {
            const int row = t >> 3, f4 = t & 7;
            const int tok = tgt_ids[r0 + row];
            ((float4*)&tg[row][0])[f4] =
                ((const float4*)(cat_emb + (size_t)tok * 32))[f4];
        }
        if (t >= 64 && t < 104) {
            const int x = t - 64;
            nm[x / 10][x % 10] = nums[(r0 + x / 10) * NNUM_ + x % 10];
        }
        __syncthreads();

        // q[w][:] = tg[w] @ Wq  (wave w owns row w; lane covers a, a+64)
        {
            const int w = t >> 6, lane = t & 63;
            float q0 = 0.f, q1 = 0.f;
#pragma unroll
            for (int e = 0; e < E_; ++e) {
                float te = tg[w][e];
                q0 += te * Wq[e * A_ + lane];
                q1 += te * Wq[e * A_ + lane + 64];
            }
            qs[w][lane] = q0; qs[w][lane + 64] = q1;
        }

        // cat_pool partials
        {
            const int iseg = t >> 5;
            const int row = (t >> 3) & 3;
            const int c0 = (t & 7) * 4;
            float4 acc = make_float4(0.f, 0.f, 0.f, 0.f);
            const int i0 = iseg * 80;
            for (int i = i0; i < i0 + 80; ++i) {
                float4 wv = *(const float4*)(Wpool + i * 32 + c0);
                fma4(acc, ce[row][i], wv);
            }
            *(float4*)&part[iseg][row][c0] = acc;
        }
        __syncthreads();

        if (t < 128) {
            const int row = t >> 5, c = t & 31;
            const int b = r0 + row;
            float s = bpool[c];
#pragma unroll
            for (int g = 0; g < 8; ++g) s += part[g][row][c];
            fused[b * 128 + 64 + c] = s;
            fused[b * 128 + c] = tg[row][c];

            float ne = bnum[c];
#pragma unroll
            for (int n = 0; n < NNUM_; ++n) ne += nm[row][n] * Wnum[n * 32 + c];
            fused[b * 128 + 96 + c] = ne;

            float pv = 0.f;
#pragma unroll 8
            for (int a = 0; a < A_; ++a) pv += Wk[c * A_ + a] * qs[row][a];
            p_out[b * 32 + c] = pv;
        }
        return;
    }

    if (blk < 1280) {
        // ---------------- seq_emb fp16 convert ----------------
        int x = (blk - 256) * 256 + t;
        for (; x < 800016; x += 1024 * 256) {
            float2 v = ((const float2*)seq_emb)[x];
            seq_h2[x] = __float22half2_rn(v);
        }
        return;
    }

    if (blk < 1284) {
        // ---------------- M = Wv @ Wo ----------------
        const int o = (blk - 1280) * 256 + t;
        const int j = o >> 5, e = o & 31;
        float sm = 0.f;
#pragma unroll 8
        for (int a = 0; a < A_; ++a) sm += Wv[j * A_ + a] * Wo[a * E_ + e];
        M[o] = sm;
        return;
    }

    if (blk < 1348) {
        // ---------------- pack half2(W1,W2) ----------------
        int x = (blk - 1284) * 256 + t;
        for (; x < 65536; x += 64 * 256) {
            W12_1[x] = __float22half2_rn(make_float2(q1W1[x], q1W2[x]));
            W12_2[x] = __float22half2_rn(make_float2(q2W1[x], q2W2[x]));
        }
        return;
    }

    {
        // ---------------- Wmlp / Wp1 / Wp2 fp16 ----------------
        int x = (blk - 1348) * 256 + t;
        for (; x < 16384; x += 8 * 256) {
            Wmlp_h2[x] = __float22half2_rn(((const float2*)Wmlp)[x]);
            Wp1_h2[x]  = __float22half2_rn(((const float2*)q1Wp)[x]);
            Wp2_h2[x]  = __float22half2_rn(((const float2*)q2Wp)[x]);
        }
    }
}

// ---------------------------------------------------------------------------
// K2: fused score + top-30 + softmax + interest.  1024 blocks x 512 threads.
//   Gather phase: 8 waves, 2 tokens/thread; selection: R4-proven wave-0 code.
// ---------------------------------------------------------------------------
__global__ __launch_bounds__(512) void score_topk_kernel(
    const int* __restrict__ seqs, const __half* __restrict__ seq_h,
    const float* __restrict__ seq_emb, const float* __restrict__ p,
    const float* __restrict__ M, const float* __restrict__ bo,
    float* __restrict__ fused)
{
    const int b = blockIdx.x;
    const int t = threadIdx.x;

    __shared__ float sc[L_];
    __shared__ float ps[E_];
    __shared__ float sw[TOPK_];
    __shared__ int   stok[TOPK_];

    if (t < E_) ps[t] = p[b * E_ + t];
    __syncthreads();

    // ---- scores: 2 tokens / thread, 8 independent 16B row loads in flight
    {
        const int tok1 = seqs[b * L_ + t];
        const int tok2 = seqs[b * L_ + t + 512];
        float4 buf[2][4];
        const float4* r1 = (const float4*)(seq_h + (size_t)tok1 * 32);
        const float4* r2 = (const float4*)(seq_h + (size_t)tok2 * 32);
#pragma unroll
        for (int i = 0; i < 4; ++i) buf[0][i] = r1[i];
#pragma unroll
        for (int i = 0; i < 4; ++i) buf[1][i] = r2[i];

        float acc0 = 0.f, acc1 = 0.f;
#pragma unroll
        for (int i = 0; i < 4; ++i) {
            const __half2* h1 = (const __half2*)&buf[0][i];
            const __half2* h2 = (const __half2*)&buf[1][i];
#pragma unroll
            for (int u = 0; u < 4; ++u) {
                float2 f1 = __half22float2(h1[u]);
                float2 f2 = __half22float2(h2[u]);
                acc0 += f1.x * ps[i * 8 + 2 * u] + f1.y * ps[i * 8 + 2 * u + 1];
                acc1 += f2.x * ps[i * 8 + 2 * u] + f2.y * ps[i * 8 + 2 * u + 1];
            }
        }
        sc[t] = acc0 * INV_SQRT_A;
        sc[t + 512] = acc1 * INV_SQRT_A;
    }
    __syncthreads();

    if (t >= 64) return;   // wave 0 only from here (R4-proven code below)

    const int lane = t;
    float v[16];
#pragma unroll
    for (int j = 0; j < 16; ++j) v[j] = sc[j * 64 + lane];   // token = j*64+lane

    float lmax = v[0]; int lj = 0;
#pragma unroll
    for (int j = 1; j < 16; ++j) if (v[j] > lmax) { lmax = v[j]; lj = j; }

    float myv = -1e30f; int myl = 0;   // lane k holds the k-th selection
    for (int k = 0; k < TOPK_; ++k) {
        float best = lmax; int bl = lj * 64 + lane;
#pragma unroll
        for (int off = 32; off > 0; off >>= 1) {
            float ov = __shfl_xor(best, off);
            int   ol = __shfl_xor(bl, off);
            if (ov > best || (ov == best && ol < bl)) { best = ov; bl = ol; }
        }
        if (lane == k) { myv = best; myl = bl; }
        if (lane == (bl & 63)) {       // owner lane: zap + recompute local max
            v[bl >> 6] = -1e30f;
            lmax = v[0]; lj = 0;
#pragma unroll
            for (int j = 1; j < 16; ++j) if (v[j] > lmax) { lmax = v[j]; lj = j; }
        }
    }

    // ---- softmax over the 30 selected
    float m = myv;
#pragma unroll
    for (int off = 32; off > 0; off >>= 1) m = fmaxf(m, __shfl_xor(m, off));
    float e = (lane < TOPK_) ? expf(myv - m) : 0.f;
    float s = e;
#pragma unroll
    for (int off = 32; off > 0; off >>= 1) s += __shfl_xor(s, off);
    if (lane < TOPK_) {
        sw[lane]   = e / s;
        stok[lane] = seqs[b * L_ + myl];
    }

    // ---- ebar from fp32 table, then interest = ebar @ M + bo
    if (lane < E_) {
        float acc = 0.f;
#pragma unroll
        for (int k = 0; k < TOPK_; ++k)
            acc += sw[k] * seq_emb[(size_t)stok[k] * 32 + lane];
        sc[lane] = acc;
    }
    if (lane < E_) {
        float acc = bo[lane];
#pragma unroll
        for (int j = 0; j < E_; ++j) acc += sc[j] * M[j * E_ + lane];
        fused[b * 128 + 32 + lane] = acc;
    }
}

// ---------------------------------------------------------------------------
// K3: MLP chain, fp16 packed weights. 256 blocks x 512 threads, RM=4.
// ---------------------------------------------------------------------------
#define RM 4
__global__ __launch_bounds__(512) void mlp_kernel(
    const float* __restrict__ fused,
    const __half* __restrict__ Wmlp_h, const float* __restrict__ bmlp,
    const __half2* __restrict__ W12_1, const float* __restrict__ b11,
    const float* __restrict__ b12, const __half* __restrict__ Wp1_h,
    const float* __restrict__ b1p,
    const __half2* __restrict__ W12_2, const float* __restrict__ b21,
    const float* __restrict__ b22, const __half* __restrict__ Wp2_h,
    const float* __restrict__ b2p,
    const float* __restrict__ Wout, const float* __restrict__ bout,
    float* __restrict__ out)
{
    const int b0 = blockIdx.x * RM;
    const int tid = threadIdx.x;
    const int cg = tid & 63;
    const int iseg = tid >> 6;
    const int c0 = cg * 4;

    __shared__ float xs[RM][128];
    __shared__ float hs[RM][H_];
    __shared__ float ts[RM][H_];
    __shared__ float part[2][8][RM][H_];
    __shared__ float red[8];

    for (int i = tid; i < RM * 128; i += 512) xs[i >> 7][i & 127] = fused[b0 * 128 + i];
    __syncthreads();

    {
        float4 acc[RM];
#pragma unroll
        for (int r = 0; r < RM; ++r) acc[r] = make_float4(0.f, 0.f, 0.f, 0.f);
        const int i0 = iseg * 16;
#pragma unroll
        for (int iq = 0; iq < 4; ++iq) {
            const int i = i0 + iq * 4;
            float4 w[4], xv[RM];
#pragma unroll
            for (int u = 0; u < 4; ++u) w[u] = ldh4(Wmlp_h + (i + u) * H_ + c0);
#pragma unroll
            for (int r = 0; r < RM; ++r) xv[r] = *(const float4*)(&xs[r][i]);
#pragma unroll
            for (int r = 0; r < RM; ++r) {
                fma4(acc[r], xv[r].x, w[0]); fma4(acc[r], xv[r].y, w[1]);
                fma4(acc[r], xv[r].z, w[2]); fma4(acc[r], xv[r].w, w[3]);
            }
        }
#pragma unroll
        for (int r = 0; r < RM; ++r) *(float4*)&part[0][iseg][r][c0] = acc[r];
    }
    __syncthreads();
    for (int o = tid; o < RM * H_; o += 512) {
        const int r = o >> 8, c = o & 255;
        float s = bmlp[c];
#pragma unroll
        for (int sg = 0; sg < 8; ++sg) s += part[0][sg][r][c];
        hs[r][c] = fmaxf(s, 0.f);
    }
    __syncthreads();

    const __half2* W12s[2] = { W12_1, W12_2 };
    const float* b1s[2] = { b11, b21 }; const float* b2s[2] = { b12, b22 };
    const __half* Wps[2] = { Wp1_h, Wp2_h }; const float* bps[2] = { b1p, b2p };

    for (int q = 0; q < 2; ++q) {
        const __half2* __restrict__ W12 = W12s[q];
        const __half*  __restrict__ Wp  = Wps[q];
        {
            float4 a1[RM], a2[RM];
#pragma unroll
            for (int r = 0; r < RM; ++r) {
                a1[r] = make_float4(0.f, 0.f, 0.f, 0.f);
                a2[r] = make_float4(0.f, 0.f, 0.f, 0.f);
            }
            const int i0 = iseg * 32;
#pragma unroll 2
            for (int iq = 0; iq < 8; ++iq) {
                const int i = i0 + iq * 4;
                float4 w1[4], w2[4], hv[RM];
#pragma unroll
                for (int u = 0; u < 4; ++u) ldh24(W12 + (i + u) * H_ + c0, w1[u], w2[u]);
#pragma unroll
                for (int r = 0; r < RM; ++r) hv[r] = *(const float4*)(&hs[r][i]);
#pragma unroll
                for (int r = 0; r < RM; ++r) {
                    fma4(a1[r], hv[r].x, w1[0]); fma4(a1[r], hv[r].y, w1[1]);
                    fma4(a1[r], hv[r].z, w1[2]); fma4(a1[r], hv[r].w, w1[3]);
                    fma4(a2[r], hv[r].x, w2[0]); fma4(a2[r], hv[r].y, w2[1]);
                    fma4(a2[r], hv[r].z, w2[2]); fma4(a2[r], hv[r].w, w2[3]);
                }
            }
#pragma unroll
            for (int r = 0; r < RM; ++r) {
                *(float4*)&part[0][iseg][r][c0] = a1[r];
                *(float4*)&part[1][iseg][r][c0] = a2[r];
            }
        }
        __syncthreads();
        {
            const float* b1 = b1s[q]; const float* b2 = b2s[q];
            for (int o = tid; o < RM * H_; o += 512) {
                const int r = o >> 8, c = o & 255;
                float t1 = b1[c], t2 = b2[c];
#pragma unroll
                for (int sg = 0; sg < 8; ++sg) { t1 += part[0][sg][r][c]; t2 += part[1][sg][r][c]; }
                ts[r][c] = t1 * t2;
            }
        }
        __syncthreads();
        {
            float4 ap[RM];
#pragma unroll
            for (int r = 0; r < RM; ++r) ap[r] = make_float4(0.f, 0.f, 0.f, 0.f);
            const int i0 = iseg * 32;
#pragma unroll 2
            for (int iq = 0; iq < 8; ++iq) {
                const int i = i0 + iq * 4;
                float4 w[4], tv[RM];
#pragma unroll
                for (int u = 0; u < 4; ++u) w[u] = ldh4(Wp + (i + u) * H_ + c0);
#pragma unroll
                for (int r = 0; r < RM; ++r) tv[r] = *(const float4*)(&ts[r][i]);
#pragma unroll
                for (int r = 0; r < RM; ++r) {
                    fma4(ap[r], tv[r].x, w[0]); fma4(ap[r], tv[r].y, w[1]);
                    fma4(ap[r], tv[r].z, w[2]); fma4(ap[r], tv[r].w, w[3]);
                }
            }
#pragma unroll
            for (int r = 0; r < RM; ++r) *(float4*)&part[0][iseg][r][c0] = ap[r];
        }
        __syncthreads();
        {
            const float* bp = bps[q];
            for (int o = tid; o < RM * H_; o += 512) {
                const int r = o >> 8, c = o & 255;
                float s = bp[c];
#pragma unroll
                for (int sg = 0; sg < 8; ++sg) s += part[0][sg][r][c];
                hs[r][c] += s;
            }
        }
        __syncthreads();
    }

    {
        const int r = tid >> 7, jj = tid & 127;
        float sum = hs[r][jj] * Wout[jj] + hs[r][jj + 128] * Wout[jj + 128];
#pragma unroll
        for (int off = 32; off > 0; off >>= 1) sum += __shfl_down(sum, off);
        if ((tid & 63) == 0) red[tid >> 6] = sum;
        __syncthreads();
        if (tid < RM) out[b0 + tid] = red[2 * tid] + red[2 * tid + 1] + bout[0];
    }
}

// ---------------------------------------------------------------------------
extern "C" void kernel_launch(void* const* d_in, const int* in_sizes, int n_in,
                              void* d_out, int out_size, void* d_ws, size_t ws_size,
                              hipStream_t stream) {
    const int*   cats    = (const int*)d_in[0];
    const float* nums    = (const float*)d_in[1];
    const int*   seqs    = (const int*)d_in[2];
    const int*   tgt_ids = (const int*)d_in[3];
    const float* cat_emb = (const float*)d_in[4];
    const float* seq_emb = (const float*)d_in[5];
    const float* Wnum    = (const float*)d_in[6];
    const float* bnum    = (const float*)d_in[7];
    const float* Wq      = (const float*)d_in[8];
    const float* Wk      = (const float*)d_in[9];
    const float* Wv      = (const float*)d_in[10];
    const float* Wo      = (const float*)d_in[11];
    const float* bo      = (const float*)d_in[12];
    const float* Wpool   = (const float*)d_in[13];
    const float* bpool   = (const float*)d_in[14];
    const float* Wmlp    = (const float*)d_in[15];
    const float* bmlp    = (const float*)d_in[16];
    const float* q1_W1   = (const float*)d_in[17];
    const float* q1_b1   = (const float*)d_in[18];
    const float* q1_W2   = (const float*)d_in[19];
    const float* q1_b2   = (const float*)d_in[20];
    const float* q1_Wp   = (const float*)d_in[21];
    const float* q1_bp   = (const float*)d_in[22];
    const float* q2_W1   = (const float*)d_in[23];
    const float* q2_b1   = (const float*)d_in[24];
    const float* q2_W2   = (const float*)d_in[25];
    const float* q2_b2   = (const float*)d_in[26];
    const float* q2_Wp   = (const float*)d_in[27];
    const float* q2_bp   = (const float*)d_in[28];
    const float* Wout    = (const float*)d_in[29];
    const float* bout    = (const float*)d_in[30];

    // Workspace layout (float-slot offsets). NOTE: one half2 == one float slot
    // (4 B). seq_h2 needs 800016 slots (padded 800064) — the R5/R6 bug was
    // halving this and overlapping the weight buffers with the fp16 table.
    float* ws = (float*)d_ws;
    float*   p       = ws;                         //      0 .. 32768
    float*   fused   = ws + 32768;                 //  32768 .. 163840
    float*   M       = ws + 163840;                // 163840 .. 164864
    __half2* seq_h2  = (__half2*)(ws + 164864);    // 164864 .. 964928 (800064)
    __half2* Wmlp_h2 = (__half2*)(ws + 964928);    // 964928 .. 981312
    __half2* W12_1   = (__half2*)(ws + 981312);    // 981312 .. 1046848
    __half2* W12_2   = (__half2*)(ws + 1046848);   // 1046848 .. 1112384
    __half2* Wp1_h2  = (__half2*)(ws + 1112384);   // 1112384 .. 1128768
    __half2* Wp2_h2  = (__half2*)(ws + 1128768);   // 1128768 .. 1145152 (4.58 MB)

    float* out = (float*)d_out;

    fused_prep_kernel<<<K1_GRID, 256, 0, stream>>>(
        cats, nums, tgt_ids, cat_emb, Wnum, bnum, Wq, Wk, Wv, Wo,
        Wpool, bpool, seq_emb, Wmlp,
        q1_W1, q1_W2, q2_W1, q2_W2, q1_Wp, q2_Wp,
        p, fused, M, seq_h2, Wmlp_h2, W12_1, W12_2, Wp1_h2, Wp2_h2);

    score_topk_kernel<<<B_, 512, 0, stream>>>(
        seqs, (const __half*)seq_h2, seq_emb, p, M, bo, fused);

    mlp_kernel<<<B_ / RM, 512, 0, stream>>>(
        fused, (const __half*)Wmlp_h2, bmlp,
        W12_1, q1_b1, q1_b2, (const __half*)Wp1_h2, q1_bp,
        W12_2, q2_b1, q2_b2, (const __half*)Wp2_h2, q2_bp,
        Wout, bout, out);
}

// Round 8
// 194.369 us; speedup vs baseline: 1.2675x; 1.0034x over previous
//
#include <hip/hip_runtime.h>
#include <hip/hip_fp16.h>

#define B_ 1024
#define L_ 1024
#define NCAT_ 20
#define NNUM_ 10
#define E_ 32
#define A_ 128
#define H_ 256
#define TOPK_ 30
#define INV_SQRT_A 0.08838834764831845f

__device__ __forceinline__ void fma4(float4& a, float s, const float4 w) {
    a.x += s * w.x; a.y += s * w.y; a.z += s * w.z; a.w += s * w.w;
}
__device__ __forceinline__ float4 ldh4(const __half* p) {
    float2 rw = *(const float2*)p;
    const __half2* h = (const __half2*)&rw;
    float2 a = __half22float2(h[0]);
    float2 b = __half22float2(h[1]);
    return make_float4(a.x, a.y, b.x, b.y);
}
__device__ __forceinline__ void ldh24(const __half2* p, float4& w1, float4& w2) {
    float4 rw = *(const float4*)p;
    const __half2* h = (const __half2*)&rw;
    float2 f0 = __half22float2(h[0]), f1 = __half22float2(h[1]);
    float2 f2 = __half22float2(h[2]), f3 = __half22float2(h[3]);
    w1 = make_float4(f0.x, f1.x, f2.x, f3.x);
    w2 = make_float4(f0.y, f1.y, f2.y, f3.y);
}

// ---------------------------------------------------------------------------
// K1: multi-role fused kernel (grid 1356 x 256) — unchanged from R7 (proven).
// ---------------------------------------------------------------------------
#define K1_GRID 1356
__global__ __launch_bounds__(256) void fused_prep_kernel(
    const int* __restrict__ cats, const float* __restrict__ nums,
    const int* __restrict__ tgt_ids, const float* __restrict__ cat_emb,
    const float* __restrict__ Wnum, const float* __restrict__ bnum,
    const float* __restrict__ Wq, const float* __restrict__ Wk,
    const float* __restrict__ Wv, const float* __restrict__ Wo,
    const float* __restrict__ Wpool, const float* __restrict__ bpool,
    const float* __restrict__ seq_emb, const float* __restrict__ Wmlp,
    const float* __restrict__ q1W1, const float* __restrict__ q1W2,
    const float* __restrict__ q2W1, const float* __restrict__ q2W2,
    const float* __restrict__ q1Wp, const float* __restrict__ q2Wp,
    float* __restrict__ p_out, float* __restrict__ fused, float* __restrict__ M,
    __half2* __restrict__ seq_h2, __half2* __restrict__ Wmlp_h2,
    __half2* __restrict__ W12_1, __half2* __restrict__ W12_2,
    __half2* __restrict__ Wp1_h2, __half2* __restrict__ Wp2_h2)
{
    const int blk = blockIdx.x;
    const int t = threadIdx.x;

    if (blk < 256) {
        __shared__ float ce[4][NCAT_ * E_];
        __shared__ float tg[4][E_];
        __shared__ float nm[4][NNUM_];
        __shared__ float qs[4][A_];
        __shared__ float part[8][4][E_];
        const int r0 = blk * 4;

        for (int idx = t; idx < 640; idx += 256) {
            const int q = idx >> 3, f4 = idx & 7;
            const int row = q / 20, cat = q % 20;
            const int tok = cats[(r0 + row) * NCAT_ + cat];
            ((float4*)&ce[row][cat * 32])[f4] =
                ((const float4*)(cat_emb + (size_t)tok * 32))[f4];
        }
        if (t < 32) {
            const int row = t >> 3, f4 = t & 7;
            const int tok = tgt_ids[r0 + row];
            ((float4*)&tg[row][0])[f4] =
                ((const float4*)(cat_emb + (size_t)tok * 32))[f4];
        }
        if (t >= 64 && t < 104) {
            const int x = t - 64;
            nm[x / 10][x % 10] = nums[(r0 + x / 10) * NNUM_ + x % 10];
        }
        __syncthreads();

        {
            const int w = t >> 6, lane = t & 63;
            float q0 = 0.f, q1 = 0.f;
#pragma unroll
            for (int e = 0; e < E_; ++e) {
                float te = tg[w][e];
                q0 += te * Wq[e * A_ + lane];
                q1 += te * Wq[e * A_ + lane + 64];
            }
            qs[w][lane] = q0; qs[w][lane + 64] = q1;
        }

        {
            const int iseg = t >> 5;
            const int row = (t >> 3) & 3;
            const int c0 = (t & 7) * 4;
            float4 acc = make_float4(0.f, 0.f, 0.f, 0.f);
            const int i0 = iseg * 80;
            for (int i = i0; i < i0 + 80; ++i) {
                float4 wv = *(const float4*)(Wpool + i * 32 + c0);
                fma4(acc, ce[row][i], wv);
            }
            *(float4*)&part[iseg][row][c0] = acc;
        }
        __syncthreads();

        if (t < 128) {
            const int row = t >> 5, c = t & 31;
            const int b = r0 + row;
            float s = bpool[c];
#pragma unroll
            for (int g = 0; g < 8; ++g) s += part[g][row][c];
            fused[b * 128 + 64 + c] = s;
            fused[b * 128 + c] = tg[row][c];

            float ne = bnum[c];
#pragma unroll
            for (int n = 0; n < NNUM_; ++n) ne += nm[row][n] * Wnum[n * 32 + c];
            fused[b * 128 + 96 + c] = ne;

            float pv = 0.f;
#pragma unroll 8
            for (int a = 0; a < A_; ++a) pv += Wk[c * A_ + a] * qs[row][a];
            p_out[b * 32 + c] = pv;
        }
        return;
    }

    if (blk < 1280) {
        int x = (blk - 256) * 256 + t;
        for (; x < 800016; x += 1024 * 256) {
            float2 v = ((const float2*)seq_emb)[x];
            seq_h2[x] = __float22half2_rn(v);
        }
        return;
    }

    if (blk < 1284) {
        const int o = (blk - 1280) * 256 + t;
        const int j = o >> 5, e = o & 31;
        float sm = 0.f;
#pragma unroll 8
        for (int a = 0; a < A_; ++a) sm += Wv[j * A_ + a] * Wo[a * E_ + e];
        M[o] = sm;
        return;
    }

    if (blk < 1348) {
        int x = (blk - 1284) * 256 + t;
        for (; x < 65536; x += 64 * 256) {
            W12_1[x] = __float22half2_rn(make_float2(q1W1[x], q1W2[x]));
            W12_2[x] = __float22half2_rn(make_float2(q2W1[x], q2W2[x]));
        }
        return;
    }

    {
        int x = (blk - 1348) * 256 + t;
        for (; x < 16384; x += 8 * 256) {
            Wmlp_h2[x] = __float22half2_rn(((const float2*)Wmlp)[x]);
            Wp1_h2[x]  = __float22half2_rn(((const float2*)q1Wp)[x]);
            Wp2_h2[x]  = __float22half2_rn(((const float2*)q2Wp)[x]);
        }
    }
}

// ---------------------------------------------------------------------------
// K2: score + top-30 + softmax + interest + MLP, fused.  256 blocks x 512
// threads, 4 rows/block.  128 threads/row gather+score (R7-proven loads);
// waves 0-3 run R4-proven selection one row per wave; interest -> LDS xs;
// then the R7-proven MLP phase on LDS-resident xs.
// ---------------------------------------------------------------------------
#define RM 4
__global__ __launch_bounds__(512) void score_mlp_kernel(
    const int* __restrict__ seqs, const __half* __restrict__ seq_h,
    const float* __restrict__ seq_emb, const float* __restrict__ p,
    const float* __restrict__ M, const float* __restrict__ bo,
    const float* __restrict__ fused,
    const __half* __restrict__ Wmlp_h, const float* __restrict__ bmlp,
    const __half2* __restrict__ W12_1, const float* __restrict__ b11,
    const float* __restrict__ b12, const __half* __restrict__ Wp1_h,
    const float* __restrict__ b1p,
    const __half2* __restrict__ W12_2, const float* __restrict__ b21,
    const float* __restrict__ b22, const __half* __restrict__ Wp2_h,
    const float* __restrict__ b2p,
    const float* __restrict__ Wout, const float* __restrict__ bout,
    float* __restrict__ out)
{
    const int b0 = blockIdx.x * RM;
    const int tid = threadIdx.x;

    __shared__ float sc[RM][L_];        // 16 KB (score rows; reused as ebar)
    __shared__ float ps[RM][E_];
    __shared__ float sw[RM][32];
    __shared__ int   stok[RM][32];
    __shared__ float xs[RM][128];
    __shared__ float hs[RM][H_];
    __shared__ float ts[RM][H_];
    __shared__ float part[2][8][RM][H_]; // 64 KB
    __shared__ float red[8];

    if (tid < 128) ps[tid >> 5][tid & 31] = p[(b0 + (tid >> 5)) * 32 + (tid & 31)];
    __syncthreads();

    // ---- Phase A: scores. row = tid>>7, 128 threads/row, 8 tokens/thread
    {
        const int row = tid >> 7;
        const int s = tid & 127;
        const int bb = b0 + row;
#pragma unroll
        for (int jj = 0; jj < 4; ++jj) {
            const int l1 = jj * 256 + s;
            const int l2 = l1 + 128;
            const int tok1 = seqs[bb * L_ + l1];
            const int tok2 = seqs[bb * L_ + l2];
            float4 buf[2][4];
            const float4* r1 = (const float4*)(seq_h + (size_t)tok1 * 32);
            const float4* r2 = (const float4*)(seq_h + (size_t)tok2 * 32);
#pragma unroll
            for (int i = 0; i < 4; ++i) buf[0][i] = r1[i];
#pragma unroll
            for (int i = 0; i < 4; ++i) buf[1][i] = r2[i];

            float acc0 = 0.f, acc1 = 0.f;
#pragma unroll
            for (int i = 0; i < 4; ++i) {
                const __half2* h1 = (const __half2*)&buf[0][i];
                const __half2* h2 = (const __half2*)&buf[1][i];
#pragma unroll
                for (int u = 0; u < 4; ++u) {
                    float2 f1 = __half22float2(h1[u]);
                    float2 f2 = __half22float2(h2[u]);
                    acc0 += f1.x * ps[row][i * 8 + 2 * u] + f1.y * ps[row][i * 8 + 2 * u + 1];
                    acc1 += f2.x * ps[row][i * 8 + 2 * u] + f2.y * ps[row][i * 8 + 2 * u + 1];
                }
            }
            sc[row][l1] = acc0 * INV_SQRT_A;
            sc[row][l2] = acc1 * INV_SQRT_A;
        }
    }
    // xs cols 0-31 and 64-127 from K1's fused (interest cols filled below)
    if (tid < 384) {
        const int r = tid / 96, c0 = tid % 96;
        const int c = (c0 < 32) ? c0 : (c0 + 32);
        xs[r][c] = fused[(b0 + r) * 128 + c];
    }
    __syncthreads();

    // ---- Phase B: selection, one row per wave (waves 0-3). R4-proven code.
    if (tid < 256) {
        const int w = tid >> 6;
        const int lane = tid & 63;
        const int bb = b0 + w;

        float v[16];
#pragma unroll
        for (int j = 0; j < 16; ++j) v[j] = sc[w][j * 64 + lane];

        float lmax = v[0]; int lj = 0;
#pragma unroll
        for (int j = 1; j < 16; ++j) if (v[j] > lmax) { lmax = v[j]; lj = j; }

        float myv = -1e30f; int myl = 0;
        for (int k = 0; k < TOPK_; ++k) {
            float best = lmax; int bl = lj * 64 + lane;
#pragma unroll
            for (int off = 32; off > 0; off >>= 1) {
                float ov = __shfl_xor(best, off);
                int   ol = __shfl_xor(bl, off);
                if (ov > best || (ov == best && ol < bl)) { best = ov; bl = ol; }
            }
            if (lane == k) { myv = best; myl = bl; }
            if (lane == (bl & 63)) {
                v[bl >> 6] = -1e30f;
                lmax = v[0]; lj = 0;
#pragma unroll
                for (int j = 1; j < 16; ++j) if (v[j] > lmax) { lmax = v[j]; lj = j; }
            }
        }

        float m = myv;
#pragma unroll
        for (int off = 32; off > 0; off >>= 1) m = fmaxf(m, __shfl_xor(m, off));
        float e = (lane < TOPK_) ? expf(myv - m) : 0.f;
        float s = e;
#pragma unroll
        for (int off = 32; off > 0; off >>= 1) s += __shfl_xor(s, off);
        if (lane < TOPK_) {
            sw[w][lane]   = e / s;
            stok[w][lane] = seqs[bb * L_ + myl];
        }

        if (lane < E_) {
            float acc = 0.f;
#pragma unroll
            for (int k = 0; k < TOPK_; ++k)
                acc += sw[w][k] * seq_emb[(size_t)stok[w][k] * 32 + lane];
            sc[w][lane] = acc;   // ebar (sc row is free now; same-wave r/w)
        }
        if (lane < E_) {
            float acc = bo[lane];
#pragma unroll
            for (int j = 0; j < E_; ++j) acc += sc[w][j] * M[j * E_ + lane];
            xs[w][32 + lane] = acc;   // interest -> LDS, no global round-trip
        }
    }
    __syncthreads();

    // ---- Phase C: MLP (R7-proven), xs already in LDS.
    const int cg = tid & 63;
    const int iseg = tid >> 6;
    const int c0 = cg * 4;

    {
        float4 acc[RM];
#pragma unroll
        for (int r = 0; r < RM; ++r) acc[r] = make_float4(0.f, 0.f, 0.f, 0.f);
        const int i0 = iseg * 16;
#pragma unroll
        for (int iq = 0; iq < 4; ++iq) {
            const int i = i0 + iq * 4;
            float4 w[4], xv[RM];
#pragma unroll
            for (int u = 0; u < 4; ++u) w[u] = ldh4(Wmlp_h + (i + u) * H_ + c0);
#pragma unroll
            for (int r = 0; r < RM; ++r) xv[r] = *(const float4*)(&xs[r][i]);
#pragma unroll
            for (int r = 0; r < RM; ++r) {
                fma4(acc[r], xv[r].x, w[0]); fma4(acc[r], xv[r].y, w[1]);
                fma4(acc[r], xv[r].z, w[2]); fma4(acc[r], xv[r].w, w[3]);
            }
        }
#pragma unroll
        for (int r = 0; r < RM; ++r) *(float4*)&part[0][iseg][r][c0] = acc[r];
    }
    __syncthreads();
    for (int o = tid; o < RM * H_; o += 512) {
        const int r = o >> 8, c = o & 255;
        float s = bmlp[c];
#pragma unroll
        for (int sg = 0; sg < 8; ++sg) s += part[0][sg][r][c];
        hs[r][c] = fmaxf(s, 0.f);
    }
    __syncthreads();

    const __half2* W12s[2] = { W12_1, W12_2 };
    const float* b1s[2] = { b11, b21 }; const float* b2s[2] = { b12, b22 };
    const __half* Wps[2] = { Wp1_h, Wp2_h }; const float* bps[2] = { b1p, b2p };

    for (int q = 0; q < 2; ++q) {
        const __half2* __restrict__ W12 = W12s[q];
        const __half*  __restrict__ Wp  = Wps[q];
        {
            float4 a1[RM], a2[RM];
#pragma unroll
            for (int r = 0; r < RM; ++r) {
                a1[r] = make_float4(0.f, 0.f, 0.f, 0.f);
                a2[r] = make_float4(0.f, 0.f, 0.f, 0.f);
            }
            const int i0 = iseg * 32;
#pragma unroll 2
            for (int iq = 0; iq < 8; ++iq) {
                const int i = i0 + iq * 4;
                float4 w1[4], w2[4], hv[RM];
#pragma unroll
                for (int u = 0; u < 4; ++u) ldh24(W12 + (i + u) * H_ + c0, w1[u], w2[u]);
#pragma unroll
                for (int r = 0; r < RM; ++r) hv[r] = *(const float4*)(&hs[r][i]);
#pragma unroll
                for (int r = 0; r < RM; ++r) {
                    fma4(a1[r], hv[r].x, w1[0]); fma4(a1[r], hv[r].y, w1[1]);
                    fma4(a1[r], hv[r].z, w1[2]); fma4(a1[r], hv[r].w, w1[3]);
                    fma4(a2[r], hv[r].x, w2[0]); fma4(a2[r], hv[r].y, w2[1]);
                    fma4(a2[r], hv[r].z, w2[2]); fma4(a2[r], hv[r].w, w2[3]);
                }
            }
#pragma unroll
            for (int r = 0; r < RM; ++r) {
                *(float4*)&part[0][iseg][r][c0] = a1[r];
                *(float4*)&part[1][iseg][r][c0] = a2[r];
            }
        }
        __syncthreads();
        {
            const float* b1 = b1s[q]; const float* b2 = b2s[q];
            for (int o = tid; o < RM * H_; o += 512) {
                const int r = o >> 8, c = o & 255;
                float t1 = b1[c], t2 = b2[c];
#pragma unroll
                for (int sg = 0; sg < 8; ++sg) { t1 += part[0][sg][r][c]; t2 += part[1][sg][r][c]; }
                ts[r][c] = t1 * t2;
            }
        }
        __syncthreads();
        {
            float4 ap[RM];
#pragma unroll
            for (int r = 0; r < RM; ++r) ap[r] = make_float4(0.f, 0.f, 0.f, 0.f);
            const int i0 = iseg * 32;
#pragma unroll 2
            for (int iq = 0; iq < 8; ++iq) {
                const int i = i0 + iq * 4;
                float4 w[4], tv[RM];
#pragma unroll
                for (int u = 0; u < 4; ++u) w[u] = ldh4(Wp + (i + u) * H_ + c0);
#pragma unroll
                for (int r = 0; r < RM; ++r) tv[r] = *(const float4*)(&ts[r][i]);
#pragma unroll
                for (int r = 0; r < RM; ++r) {
                    fma4(ap[r], tv[r].x, w[0]); fma4(ap[r], tv[r].y, w[1]);
                    fma4(ap[r], tv[r].z, w[2]); fma4(ap[r], tv[r].w, w[3]);
                }
            }
#pragma unroll
            for (int r = 0; r < RM; ++r) *(float4*)&part[0][iseg][r][c0] = ap[r];
        }
        __syncthreads();
        {
            const float* bp = bps[q];
            for (int o = tid; o < RM * H_; o += 512) {
                const int r = o >> 8, c = o & 255;
                float s = bp[c];
#pragma unroll
                for (int sg = 0; sg < 8; ++sg) s += part[0][sg][r][c];
                hs[r][c] += s;
            }
        }
        __syncthreads();
    }

    {
        const int r = tid >> 7, jj = tid & 127;
        float sum = hs[r][jj] * Wout[jj] + hs[r][jj + 128] * Wout[jj + 128];
#pragma unroll
        for (int off = 32; off > 0; off >>= 1) sum += __shfl_down(sum, off);
        if ((tid & 63) == 0) red[tid >> 6] = sum;
        __syncthreads();
        if (tid < RM) out[b0 + tid] = red[2 * tid] + red[2 * tid + 1] + bout[0];
    }
}

// ---------------------------------------------------------------------------
extern "C" void kernel_launch(void* const* d_in, const int* in_sizes, int n_in,
                              void* d_out, int out_size, void* d_ws, size_t ws_size,
                              hipStream_t stream) {
    const int*   cats    = (const int*)d_in[0];
    const float* nums    = (const float*)d_in[1];
    const int*   seqs    = (const int*)d_in[2];
    const int*   tgt_ids = (const int*)d_in[3];
    const float* cat_emb = (const float*)d_in[4];
    const float* seq_emb = (const float*)d_in[5];
    const float* Wnum    = (const float*)d_in[6];
    const float* bnum    = (const float*)d_in[7];
    const float* Wq      = (const float*)d_in[8];
    const float* Wk      = (const float*)d_in[9];
    const float* Wv      = (const float*)d_in[10];
    const float* Wo      = (const float*)d_in[11];
    const float* bo      = (const float*)d_in[12];
    const float* Wpool   = (const float*)d_in[13];
    const float* bpool   = (const float*)d_in[14];
    const float* Wmlp    = (const float*)d_in[15];
    const float* bmlp    = (const float*)d_in[16];
    const float* q1_W1   = (const float*)d_in[17];
    const float* q1_b1   = (const float*)d_in[18];
    const float* q1_W2   = (const float*)d_in[19];
    const float* q1_b2   = (const float*)d_in[20];
    const float* q1_Wp   = (const float*)d_in[21];
    const float* q1_bp   = (const float*)d_in[22];
    const float* q2_W1   = (const float*)d_in[23];
    const float* q2_b1   = (const float*)d_in[24];
    const float* q2_W2   = (const float*)d_in[25];
    const float* q2_b2   = (const float*)d_in[26];
    const float* q2_Wp   = (const float*)d_in[27];
    const float* q2_bp   = (const float*)d_in[28];
    const float* Wout    = (const float*)d_in[29];
    const float* bout    = (const float*)d_in[30];

    // Workspace layout (float-slot offsets); one half2 == one 4 B slot.
    // seq_h2 needs 800016 slots (padded 800064) — do not shrink (R5/R6 bug).
    float* ws = (float*)d_ws;
    float*   p       = ws;                         //      0 .. 32768
    float*   fused   = ws + 32768;                 //  32768 .. 163840
    float*   M       = ws + 163840;                // 163840 .. 164864
    __half2* seq_h2  = (__half2*)(ws + 164864);    // 164864 .. 964928 (800064)
    __half2* Wmlp_h2 = (__half2*)(ws + 964928);    // 964928 .. 981312
    __half2* W12_1   = (__half2*)(ws + 981312);    // 981312 .. 1046848
    __half2* W12_2   = (__half2*)(ws + 1046848);   // 1046848 .. 1112384
    __half2* Wp1_h2  = (__half2*)(ws + 1112384);   // 1112384 .. 1128768
    __half2* Wp2_h2  = (__half2*)(ws + 1128768);   // 1128768 .. 1145152 (4.58 MB)

    float* out = (float*)d_out;

    fused_prep_kernel<<<K1_GRID, 256, 0, stream>>>(
        cats, nums, tgt_ids, cat_emb, Wnum, bnum, Wq, Wk, Wv, Wo,
        Wpool, bpool, seq_emb, Wmlp,
        q1_W1, q1_W2, q2_W1, q2_W2, q1_Wp, q2_Wp,
        p, fused, M, seq_h2, Wmlp_h2, W12_1, W12_2, Wp1_h2, Wp2_h2);

    score_mlp_kernel<<<B_ / RM, 512, 0, stream>>>(
        seqs, (const __half*)seq_h2, seq_emb, p, M, bo, fused,
        (const __half*)Wmlp_h2, bmlp,
        W12_1, q1_b1, q1_b2, (const __half*)Wp1_h2, q1_bp,
        W12_2, q2_b1, q2_b2, (const __half*)Wp2_h2, q2_bp,
        Wout, bout, out);
}

// Round 9
// 179.826 us; speedup vs baseline: 1.3700x; 1.0809x over previous
//
#include <hip/hip_runtime.h>
#include <hip/hip_fp16.h>

#define B_ 1024
#define L_ 1024
#define NCAT_ 20
#define NNUM_ 10
#define E_ 32
#define A_ 128
#define H_ 256
#define TOPK_ 30
#define INV_SQRT_A 0.08838834764831845f

__device__ __forceinline__ void fma4(float4& a, float s, const float4 w) {
    a.x += s * w.x; a.y += s * w.y; a.z += s * w.z; a.w += s * w.w;
}
__device__ __forceinline__ float4 ldh4(const __half* p) {
    float2 rw = *(const float2*)p;
    const __half2* h = (const __half2*)&rw;
    float2 a = __half22float2(h[0]);
    float2 b = __half22float2(h[1]);
    return make_float4(a.x, a.y, b.x, b.y);
}
__device__ __forceinline__ void ldh24(const __half2* p, float4& w1, float4& w2) {
    float4 rw = *(const float4*)p;
    const __half2* h = (const __half2*)&rw;
    float2 f0 = __half22float2(h[0]), f1 = __half22float2(h[1]);
    float2 f2 = __half22float2(h[2]), f3 = __half22float2(h[3]);
    w1 = make_float4(f0.x, f1.x, f2.x, f3.x);
    w2 = make_float4(f0.y, f1.y, f2.y, f3.y);
}
// monotonic float<->u32 (roundtrip exact)
__device__ __forceinline__ unsigned sortable(float f) {
    unsigned u = __float_as_uint(f);
    return (u & 0x80000000u) ? ~u : (u | 0x80000000u);
}
__device__ __forceinline__ float unsortable(unsigned s) {
    unsigned u = (s & 0x80000000u) ? (s ^ 0x80000000u) : ~s;
    return __uint_as_float(u);
}

// ---------------------------------------------------------------------------
// K1: multi-role fused kernel (grid 1356 x 256) — unchanged from R7/R8 (proven).
// ---------------------------------------------------------------------------
#define K1_GRID 1356
__global__ __launch_bounds__(256) void fused_prep_kernel(
    const int* __restrict__ cats, const float* __restrict__ nums,
    const int* __restrict__ tgt_ids, const float* __restrict__ cat_emb,
    const float* __restrict__ Wnum, const float* __restrict__ bnum,
    const float* __restrict__ Wq, const float* __restrict__ Wk,
    const float* __restrict__ Wv, const float* __restrict__ Wo,
    const float* __restrict__ Wpool, const float* __restrict__ bpool,
    const float* __restrict__ seq_emb, const float* __restrict__ Wmlp,
    const float* __restrict__ q1W1, const float* __restrict__ q1W2,
    const float* __restrict__ q2W1, const float* __restrict__ q2W2,
    const float* __restrict__ q1Wp, const float* __restrict__ q2Wp,
    float* __restrict__ p_out, float* __restrict__ fused, float* __restrict__ M,
    __half2* __restrict__ seq_h2, __half2* __restrict__ Wmlp_h2,
    __half2* __restrict__ W12_1, __half2* __restrict__ W12_2,
    __half2* __restrict__ Wp1_h2, __half2* __restrict__ Wp2_h2)
{
    const int blk = blockIdx.x;
    const int t = threadIdx.x;

    if (blk < 256) {
        __shared__ float ce[4][NCAT_ * E_];
        __shared__ float tg[4][E_];
        __shared__ float nm[4][NNUM_];
        __shared__ float qs[4][A_];
        __shared__ float part[8][4][E_];
        const int r0 = blk * 4;

        for (int idx = t; idx < 640; idx += 256) {
            const int q = idx >> 3, f4 = idx & 7;
            const int row = q / 20, cat = q % 20;
            const int tok = cats[(r0 + row) * NCAT_ + cat];
            ((float4*)&ce[row][cat * 32])[f4] =
                ((const float4*)(cat_emb + (size_t)tok * 32))[f4];
        }
        if (t < 32) {
            const int row = t >> 3, f4 = t & 7;
            const int tok = tgt_ids[r0 + row];
            ((float4*)&tg[row][0])[f4] =
                ((const float4*)(cat_emb + (size_t)tok * 32))[f4];
        }
        if (t >= 64 && t < 104) {
            const int x = t - 64;
            nm[x / 10][x % 10] = nums[(r0 + x / 10) * NNUM_ + x % 10];
        }
        __syncthreads();

        {
            const int w = t >> 6, lane = t & 63;
            float q0 = 0.f, q1 = 0.f;
#pragma unroll
            for (int e = 0; e < E_; ++e) {
                float te = tg[w][e];
                q0 += te * Wq[e * A_ + lane];
                q1 += te * Wq[e * A_ + lane + 64];
            }
            qs[w][lane] = q0; qs[w][lane + 64] = q1;
        }

        {
            const int iseg = t >> 5;
            const int row = (t >> 3) & 3;
            const int c0 = (t & 7) * 4;
            float4 acc = make_float4(0.f, 0.f, 0.f, 0.f);
            const int i0 = iseg * 80;
            for (int i = i0; i < i0 + 80; ++i) {
                float4 wv = *(const float4*)(Wpool + i * 32 + c0);
                fma4(acc, ce[row][i], wv);
            }
            *(float4*)&part[iseg][row][c0] = acc;
        }
        __syncthreads();

        if (t < 128) {
            const int row = t >> 5, c = t & 31;
            const int b = r0 + row;
            float s = bpool[c];
#pragma unroll
            for (int g = 0; g < 8; ++g) s += part[g][row][c];
            fused[b * 128 + 64 + c] = s;
            fused[b * 128 + c] = tg[row][c];

            float ne = bnum[c];
#pragma unroll
            for (int n = 0; n < NNUM_; ++n) ne += nm[row][n] * Wnum[n * 32 + c];
            fused[b * 128 + 96 + c] = ne;

            float pv = 0.f;
#pragma unroll 8
            for (int a = 0; a < A_; ++a) pv += Wk[c * A_ + a] * qs[row][a];
            p_out[b * 32 + c] = pv;
        }
        return;
    }

    if (blk < 1280) {
        int x = (blk - 256) * 256 + t;
        for (; x < 800016; x += 1024 * 256) {
            float2 v = ((const float2*)seq_emb)[x];
            seq_h2[x] = __float22half2_rn(v);
        }
        return;
    }

    if (blk < 1284) {
        const int o = (blk - 1280) * 256 + t;
        const int j = o >> 5, e = o & 31;
        float sm = 0.f;
#pragma unroll 8
        for (int a = 0; a < A_; ++a) sm += Wv[j * A_ + a] * Wo[a * E_ + e];
        M[o] = sm;
        return;
    }

    if (blk < 1348) {
        int x = (blk - 1284) * 256 + t;
        for (; x < 65536; x += 64 * 256) {
            W12_1[x] = __float22half2_rn(make_float2(q1W1[x], q1W2[x]));
            W12_2[x] = __float22half2_rn(make_float2(q2W1[x], q2W2[x]));
        }
        return;
    }

    {
        int x = (blk - 1348) * 256 + t;
        for (; x < 16384; x += 8 * 256) {
            Wmlp_h2[x] = __float22half2_rn(((const float2*)Wmlp)[x]);
            Wp1_h2[x]  = __float22half2_rn(((const float2*)q1Wp)[x]);
            Wp2_h2[x]  = __float22half2_rn(((const float2*)q2Wp)[x]);
        }
    }
}

// ---------------------------------------------------------------------------
// K2: score + top-30 + softmax + interest + MLP, fused.  256 blocks x 512.
// R8 structure; Phase B selection replaced by presorted-lane u64 pop loop
// (1 shuffle-chain per iteration instead of 2 + no local-max recompute).
// ---------------------------------------------------------------------------
#define RM 4
__global__ __launch_bounds__(512) void score_mlp_kernel(
    const int* __restrict__ seqs, const __half* __restrict__ seq_h,
    const float* __restrict__ seq_emb, const float* __restrict__ p,
    const float* __restrict__ M, const float* __restrict__ bo,
    const float* __restrict__ fused,
    const __half* __restrict__ Wmlp_h, const float* __restrict__ bmlp,
    const __half2* __restrict__ W12_1, const float* __restrict__ b11,
    const float* __restrict__ b12, const __half* __restrict__ Wp1_h,
    const float* __restrict__ b1p,
    const __half2* __restrict__ W12_2, const float* __restrict__ b21,
    const float* __restrict__ b22, const __half* __restrict__ Wp2_h,
    const float* __restrict__ b2p,
    const float* __restrict__ Wout, const float* __restrict__ bout,
    float* __restrict__ out)
{
    const int b0 = blockIdx.x * RM;
    const int tid = threadIdx.x;

    __shared__ float sc[RM][L_];        // 16 KB (score rows; reused as ebar)
    __shared__ float ps[RM][E_];
    __shared__ float sw[RM][32];
    __shared__ int   stok[RM][32];
    __shared__ float xs[RM][128];
    __shared__ float hs[RM][H_];
    __shared__ float ts[RM][H_];
    __shared__ float part[2][8][RM][H_]; // 64 KB
    __shared__ float red[8];

    if (tid < 128) ps[tid >> 5][tid & 31] = p[(b0 + (tid >> 5)) * 32 + (tid & 31)];
    __syncthreads();

    // ---- Phase A: scores. row = tid>>7, 128 threads/row, 8 tokens/thread
    {
        const int row = tid >> 7;
        const int s = tid & 127;
        const int bb = b0 + row;
#pragma unroll
        for (int jj = 0; jj < 4; ++jj) {
            const int l1 = jj * 256 + s;
            const int l2 = l1 + 128;
            const int tok1 = seqs[bb * L_ + l1];
            const int tok2 = seqs[bb * L_ + l2];
            float4 buf[2][4];
            const float4* r1 = (const float4*)(seq_h + (size_t)tok1 * 32);
            const float4* r2 = (const float4*)(seq_h + (size_t)tok2 * 32);
#pragma unroll
            for (int i = 0; i < 4; ++i) buf[0][i] = r1[i];
#pragma unroll
            for (int i = 0; i < 4; ++i) buf[1][i] = r2[i];

            float acc0 = 0.f, acc1 = 0.f;
#pragma unroll
            for (int i = 0; i < 4; ++i) {
                const __half2* h1 = (const __half2*)&buf[0][i];
                const __half2* h2 = (const __half2*)&buf[1][i];
#pragma unroll
                for (int u = 0; u < 4; ++u) {
                    float2 f1 = __half22float2(h1[u]);
                    float2 f2 = __half22float2(h2[u]);
                    acc0 += f1.x * ps[row][i * 8 + 2 * u] + f1.y * ps[row][i * 8 + 2 * u + 1];
                    acc1 += f2.x * ps[row][i * 8 + 2 * u] + f2.y * ps[row][i * 8 + 2 * u + 1];
                }
            }
            sc[row][l1] = acc0 * INV_SQRT_A;
            sc[row][l2] = acc1 * INV_SQRT_A;
        }
    }
    // xs cols 0-31 and 64-127 from K1's fused (interest cols filled below)
    if (tid < 384) {
        const int r = tid / 96, c0 = tid % 96;
        const int c = (c0 < 32) ? c0 : (c0 + 32);
        xs[r][c] = fused[(b0 + r) * 128 + c];
    }
    __syncthreads();

    // ---- Phase B: selection, one row per wave (waves 0-3).
    if (tid < 256) {
        const int w = tid >> 6;
        const int lane = tid & 63;
        const int bb = b0 + w;

        // per-lane packed keys: value (monotonic u32) << 10 | (1023 - l).
        // unique per l; lower l wins ties (matches jax.lax.top_k).
        unsigned long long key[16];
#pragma unroll
        for (int j = 0; j < 16; ++j) {
            const int l = j * 64 + lane;
            key[j] = ((unsigned long long)sortable(sc[w][l]) << 10)
                   | (unsigned)(1023 - l);
        }
        // sort descending: branchless bubble network, static indices only
#pragma unroll
        for (int a = 0; a < 15; ++a)
#pragma unroll
            for (int j = 0; j < 15 - a; ++j) {
                const bool swp = key[j] < key[j + 1];
                const unsigned long long hi = swp ? key[j + 1] : key[j];
                const unsigned long long lo = swp ? key[j] : key[j + 1];
                key[j] = hi; key[j + 1] = lo;
            }

        float myv = -1e30f; int myl = 0;   // lane k holds the k-th selection
        unsigned long long front = key[0];
        for (int k = 0; k < TOPK_; ++k) {
            unsigned long long wk = front;
#pragma unroll
            for (int off = 32; off > 0; off >>= 1) {
                unsigned long long o = __shfl_xor(wk, off);
                if (o > wk) wk = o;
            }
            if (lane == k) {
                myv = unsortable((unsigned)(wk >> 10));
                myl = 1023 - (int)(wk & 1023);
            }
            if (front == wk) {   // winner lane (keys unique): pop front
#pragma unroll
                for (int j = 0; j < 15; ++j) key[j] = key[j + 1];
                key[15] = 0ULL;
                front = key[0];
            }
        }

        // softmax over the 30 selected (identical to R8)
        float m = myv;
#pragma unroll
        for (int off = 32; off > 0; off >>= 1) m = fmaxf(m, __shfl_xor(m, off));
        float e = (lane < TOPK_) ? expf(myv - m) : 0.f;
        float s = e;
#pragma unroll
        for (int off = 32; off > 0; off >>= 1) s += __shfl_xor(s, off);
        if (lane < TOPK_) {
            sw[w][lane]   = e / s;
            stok[w][lane] = seqs[bb * L_ + myl];
        }

        if (lane < E_) {
            float acc = 0.f;
#pragma unroll
            for (int k = 0; k < TOPK_; ++k)
                acc += sw[w][k] * seq_emb[(size_t)stok[w][k] * 32 + lane];
            sc[w][lane] = acc;   // ebar (sc row free now; same-wave r/w)
        }
        if (lane < E_) {
            float acc = bo[lane];
#pragma unroll
            for (int j = 0; j < E_; ++j) acc += sc[w][j] * M[j * E_ + lane];
            xs[w][32 + lane] = acc;   // interest -> LDS
        }
    }
    __syncthreads();

    // ---- Phase C: MLP (R7/R8-proven), xs already in LDS.
    const int cg = tid & 63;
    const int iseg = tid >> 6;
    const int c0 = cg * 4;

    {
        float4 acc[RM];
#pragma unroll
        for (int r = 0; r < RM; ++r) acc[r] = make_float4(0.f, 0.f, 0.f, 0.f);
        const int i0 = iseg * 16;
#pragma unroll
        for (int iq = 0; iq < 4; ++iq) {
            const int i = i0 + iq * 4;
            float4 w[4], xv[RM];
#pragma unroll
            for (int u = 0; u < 4; ++u) w[u] = ldh4(Wmlp_h + (i + u) * H_ + c0);
#pragma unroll
            for (int r = 0; r < RM; ++r) xv[r] = *(const float4*)(&xs[r][i]);
#pragma unroll
            for (int r = 0; r < RM; ++r) {
                fma4(acc[r], xv[r].x, w[0]); fma4(acc[r], xv[r].y, w[1]);
                fma4(acc[r], xv[r].z, w[2]); fma4(acc[r], xv[r].w, w[3]);
            }
        }
#pragma unroll
        for (int r = 0; r < RM; ++r) *(float4*)&part[0][iseg][r][c0] = acc[r];
    }
    __syncthreads();
    for (int o = tid; o < RM * H_; o += 512) {
        const int r = o >> 8, c = o & 255;
        float s = bmlp[c];
#pragma unroll
        for (int sg = 0; sg < 8; ++sg) s += part[0][sg][r][c];
        hs[r][c] = fmaxf(s, 0.f);
    }
    __syncthreads();

    const __half2* W12s[2] = { W12_1, W12_2 };
    const float* b1s[2] = { b11, b21 }; const float* b2s[2] = { b12, b22 };
    const __half* Wps[2] = { Wp1_h, Wp2_h }; const float* bps[2] = { b1p, b2p };

    for (int q = 0; q < 2; ++q) {
        const __half2* __restrict__ W12 = W12s[q];
        const __half*  __restrict__ Wp  = Wps[q];
        {
            float4 a1[RM], a2[RM];
#pragma unroll
            for (int r = 0; r < RM; ++r) {
                a1[r] = make_float4(0.f, 0.f, 0.f, 0.f);
                a2[r] = make_float4(0.f, 0.f, 0.f, 0.f);
            }
            const int i0 = iseg * 32;
#pragma unroll 2
            for (int iq = 0; iq < 8; ++iq) {
                const int i = i0 + iq * 4;
                float4 w1[4], w2[4], hv[RM];
#pragma unroll
                for (int u = 0; u < 4; ++u) ldh24(W12 + (i + u) * H_ + c0, w1[u], w2[u]);
#pragma unroll
                for (int r = 0; r < RM; ++r) hv[r] = *(const float4*)(&hs[r][i]);
#pragma unroll
                for (int r = 0; r < RM; ++r) {
                    fma4(a1[r], hv[r].x, w1[0]); fma4(a1[r], hv[r].y, w1[1]);
                    fma4(a1[r], hv[r].z, w1[2]); fma4(a1[r], hv[r].w, w1[3]);
                    fma4(a2[r], hv[r].x, w2[0]); fma4(a2[r], hv[r].y, w2[1]);
                    fma4(a2[r], hv[r].z, w2[2]); fma4(a2[r], hv[r].w, w2[3]);
                }
            }
#pragma unroll
            for (int r = 0; r < RM; ++r) {
                *(float4*)&part[0][iseg][r][c0] = a1[r];
                *(float4*)&part[1][iseg][r][c0] = a2[r];
            }
        }
        __syncthreads();
        {
            const float* b1 = b1s[q]; const float* b2 = b2s[q];
            for (int o = tid; o < RM * H_; o += 512) {
                const int r = o >> 8, c = o & 255;
                float t1 = b1[c], t2 = b2[c];
#pragma unroll
                for (int sg = 0; sg < 8; ++sg) { t1 += part[0][sg][r][c]; t2 += part[1][sg][r][c]; }
                ts[r][c] = t1 * t2;
            }
        }
        __syncthreads();
        {
            float4 ap[RM];
#pragma unroll
            for (int r = 0; r < RM; ++r) ap[r] = make_float4(0.f, 0.f, 0.f, 0.f);
            const int i0 = iseg * 32;
#pragma unroll 2
            for (int iq = 0; iq < 8; ++iq) {
                const int i = i0 + iq * 4;
                float4 w[4], tv[RM];
#pragma unroll
                for (int u = 0; u < 4; ++u) w[u] = ldh4(Wp + (i + u) * H_ + c0);
#pragma unroll
                for (int r = 0; r < RM; ++r) tv[r] = *(const float4*)(&ts[r][i]);
#pragma unroll
                for (int r = 0; r < RM; ++r) {
                    fma4(ap[r], tv[r].x, w[0]); fma4(ap[r], tv[r].y, w[1]);
                    fma4(ap[r], tv[r].z, w[2]); fma4(ap[r], tv[r].w, w[3]);
                }
            }
#pragma unroll
            for (int r = 0; r < RM; ++r) *(float4*)&part[0][iseg][r][c0] = ap[r];
        }
        __syncthreads();
        {
            const float* bp = bps[q];
            for (int o = tid; o < RM * H_; o += 512) {
                const int r = o >> 8, c = o & 255;
                float s = bp[c];
#pragma unroll
                for (int sg = 0; sg < 8; ++sg) s += part[0][sg][r][c];
                hs[r][c] += s;
            }
        }
        __syncthreads();
    }

    {
        const int r = tid >> 7, jj = tid & 127;
        float sum = hs[r][jj] * Wout[jj] + hs[r][jj + 128] * Wout[jj + 128];
#pragma unroll
        for (int off = 32; off > 0; off >>= 1) sum += __shfl_down(sum, off);
        if ((tid & 63) == 0) red[tid >> 6] = sum;
        __syncthreads();
        if (tid < RM) out[b0 + tid] = red[2 * tid] + red[2 * tid + 1] + bout[0];
    }
}

// ---------------------------------------------------------------------------
extern "C" void kernel_launch(void* const* d_in, const int* in_sizes, int n_in,
                              void* d_out, int out_size, void* d_ws, size_t ws_size,
                              hipStream_t stream) {
    const int*   cats    = (const int*)d_in[0];
    const float* nums    = (const float*)d_in[1];
    const int*   seqs    = (const int*)d_in[2];
    const int*   tgt_ids = (const int*)d_in[3];
    const float* cat_emb = (const float*)d_in[4];
    const float* seq_emb = (const float*)d_in[5];
    const float* Wnum    = (const float*)d_in[6];
    const float* bnum    = (const float*)d_in[7];
    const float* Wq      = (const float*)d_in[8];
    const float* Wk      = (const float*)d_in[9];
    const float* Wv      = (const float*)d_in[10];
    const float* Wo      = (const float*)d_in[11];
    const float* bo      = (const float*)d_in[12];
    const float* Wpool   = (const float*)d_in[13];
    const float* bpool   = (const float*)d_in[14];
    const float* Wmlp    = (const float*)d_in[15];
    const float* bmlp    = (const float*)d_in[16];
    const float* q1_W1   = (const float*)d_in[17];
    const float* q1_b1   = (const float*)d_in[18];
    const float* q1_W2   = (const float*)d_in[19];
    const float* q1_b2   = (const float*)d_in[20];
    const float* q1_Wp   = (const float*)d_in[21];
    const float* q1_bp   = (const float*)d_in[22];
    const float* q2_W1   = (const float*)d_in[23];
    const float* q2_b1   = (const float*)d_in[24];
    const float* q2_W2   = (const float*)d_in[25];
    const float* q2_b2   = (const float*)d_in[26];
    const float* q2_Wp   = (const float*)d_in[27];
    const float* q2_bp   = (const float*)d_in[28];
    const float* Wout    = (const float*)d_in[29];
    const float* bout    = (const float*)d_in[30];

    // Workspace layout (float-slot offsets); one half2 == one 4 B slot.
    // seq_h2 needs 800016 slots (padded 800064) — do not shrink (R5/R6 bug).
    float* ws = (float*)d_ws;
    float*   p       = ws;                         //      0 .. 32768
    float*   fused   = ws + 32768;                 //  32768 .. 163840
    float*   M       = ws + 163840;                // 163840 .. 164864
    __half2* seq_h2  = (__half2*)(ws + 164864);    // 164864 .. 964928 (800064)
    __half2* Wmlp_h2 = (__half2*)(ws + 964928);    // 964928 .. 981312
    __half2* W12_1   = (__half2*)(ws + 981312);    // 981312 .. 1046848
    __half2* W12_2   = (__half2*)(ws + 1046848);   // 1046848 .. 1112384
    __half2* Wp1_h2  = (__half2*)(ws + 1112384);   // 1112384 .. 1128768
    __half2* Wp2_h2  = (__half2*)(ws + 1128768);   // 1128768 .. 1145152 (4.58 MB)

    float* out = (float*)d_out;

    fused_prep_kernel<<<K1_GRID, 256, 0, stream>>>(
        cats, nums, tgt_ids, cat_emb, Wnum, bnum, Wq, Wk, Wv, Wo,
        Wpool, bpool, seq_emb, Wmlp,
        q1_W1, q1_W2, q2_W1, q2_W2, q1_Wp, q2_Wp,
        p, fused, M, seq_h2, Wmlp_h2, W12_1, W12_2, Wp1_h2, Wp2_h2);

    score_mlp_kernel<<<B_ / RM, 512, 0, stream>>>(
        seqs, (const __half*)seq_h2, seq_emb, p, M, bo, fused,
        (const __half*)Wmlp_h2, bmlp,
        W12_1, q1_b1, q1_b2, (const __half*)Wp1_h2, q1_bp,
        W12_2, q2_b1, q2_b2, (const __half*)Wp2_h2, q2_bp,
        Wout, bout, out);
}

// Round 10
// 179.405 us; speedup vs baseline: 1.3732x; 1.0023x over previous
//
#include <hip/hip_runtime.h>
#include <hip/hip_fp16.h>

#define B_ 1024
#define L_ 1024
#define NCAT_ 20
#define NNUM_ 10
#define E_ 32
#define A_ 128
#define H_ 256
#define TOPK_ 30
#define INV_SQRT_A 0.08838834764831845f

__device__ __forceinline__ void fma4(float4& a, float s, const float4 w) {
    a.x += s * w.x; a.y += s * w.y; a.z += s * w.z; a.w += s * w.w;
}
__device__ __forceinline__ float4 ldh4(const __half* p) {
    float2 rw = *(const float2*)p;
    const __half2* h = (const __half2*)&rw;
    float2 a = __half22float2(h[0]);
    float2 b = __half22float2(h[1]);
    return make_float4(a.x, a.y, b.x, b.y);
}
__device__ __forceinline__ void ldh24(const __half2* p, float4& w1, float4& w2) {
    float4 rw = *(const float4*)p;
    const __half2* h = (const __half2*)&rw;
    float2 f0 = __half22float2(h[0]), f1 = __half22float2(h[1]);
    float2 f2 = __half22float2(h[2]), f3 = __half22float2(h[3]);
    w1 = make_float4(f0.x, f1.x, f2.x, f3.x);
    w2 = make_float4(f0.y, f1.y, f2.y, f3.y);
}
// monotonic float<->u32 (roundtrip exact)
__device__ __forceinline__ unsigned sortable(float f) {
    unsigned u = __float_as_uint(f);
    return (u & 0x80000000u) ? ~u : (u | 0x80000000u);
}
__device__ __forceinline__ float unsortable(unsigned s) {
    unsigned u = (s & 0x80000000u) ? (s ^ 0x80000000u) : ~s;
    return __uint_as_float(u);
}

// ---------------------------------------------------------------------------
// K1: multi-role fused kernel (grid 1356 x 256).  Same as R9 except the Wp
// conversion now covers the FULL 32768 float2 (R4-R9 converted only half;
// numerically invisible because ts~1e-6, but fixed for robustness).
// ---------------------------------------------------------------------------
#define K1_GRID 1356
__global__ __launch_bounds__(256) void fused_prep_kernel(
    const int* __restrict__ cats, const float* __restrict__ nums,
    const int* __restrict__ tgt_ids, const float* __restrict__ cat_emb,
    const float* __restrict__ Wnum, const float* __restrict__ bnum,
    const float* __restrict__ Wq, const float* __restrict__ Wk,
    const float* __restrict__ Wv, const float* __restrict__ Wo,
    const float* __restrict__ Wpool, const float* __restrict__ bpool,
    const float* __restrict__ seq_emb, const float* __restrict__ Wmlp,
    const float* __restrict__ q1W1, const float* __restrict__ q1W2,
    const float* __restrict__ q2W1, const float* __restrict__ q2W2,
    const float* __restrict__ q1Wp, const float* __restrict__ q2Wp,
    float* __restrict__ p_out, float* __restrict__ fused, float* __restrict__ M,
    __half2* __restrict__ seq_h2, __half2* __restrict__ Wmlp_h2,
    __half2* __restrict__ W12_1, __half2* __restrict__ W12_2,
    __half2* __restrict__ Wp1_h2, __half2* __restrict__ Wp2_h2)
{
    const int blk = blockIdx.x;
    const int t = threadIdx.x;

    if (blk < 256) {
        __shared__ float ce[4][NCAT_ * E_];
        __shared__ float tg[4][E_];
        __shared__ float nm[4][NNUM_];
        __shared__ float qs[4][A_];
        __shared__ float part[8][4][E_];
        const int r0 = blk * 4;

        for (int idx = t; idx < 640; idx += 256) {
            const int q = idx >> 3, f4 = idx & 7;
            const int row = q / 20, cat = q % 20;
            const int tok = cats[(r0 + row) * NCAT_ + cat];
            ((float4*)&ce[row][cat * 32])[f4] =
                ((const float4*)(cat_emb + (size_t)tok * 32))[f4];
        }
        if (t < 32) {
            const int row = t >> 3, f4 = t & 7;
            const int tok = tgt_ids[r0 + row];
            ((float4*)&tg[row][0])[f4] =
                ((const float4*)(cat_emb + (size_t)tok * 32))[f4];
        }
        if (t >= 64 && t < 104) {
            const int x = t - 64;
            nm[x / 10][x % 10] = nums[(r0 + x / 10) * NNUM_ + x % 10];
        }
        __syncthreads();

        {
            const int w = t >> 6, lane = t & 63;
            float q0 = 0.f, q1 = 0.f;
#pragma unroll
            for (int e = 0; e < E_; ++e) {
                float te = tg[w][e];
                q0 += te * Wq[e * A_ + lane];
                q1 += te * Wq[e * A_ + lane + 64];
            }
            qs[w][lane] = q0; qs[w][lane + 64] = q1;
        }

        {
            const int iseg = t >> 5;
            const int row = (t >> 3) & 3;
            const int c0 = (t & 7) * 4;
            float4 acc = make_float4(0.f, 0.f, 0.f, 0.f);
            const int i0 = iseg * 80;
            for (int i = i0; i < i0 + 80; ++i) {
                float4 wv = *(const float4*)(Wpool + i * 32 + c0);
                fma4(acc, ce[row][i], wv);
            }
            *(float4*)&part[iseg][row][c0] = acc;
        }
        __syncthreads();

        if (t < 128) {
            const int row = t >> 5, c = t & 31;
            const int b = r0 + row;
            float s = bpool[c];
#pragma unroll
            for (int g = 0; g < 8; ++g) s += part[g][row][c];
            fused[b * 128 + 64 + c] = s;
            fused[b * 128 + c] = tg[row][c];

            float ne = bnum[c];
#pragma unroll
            for (int n = 0; n < NNUM_; ++n) ne += nm[row][n] * Wnum[n * 32 + c];
            fused[b * 128 + 96 + c] = ne;

            float pv = 0.f;
#pragma unroll 8
            for (int a = 0; a < A_; ++a) pv += Wk[c * A_ + a] * qs[row][a];
            p_out[b * 32 + c] = pv;
        }
        return;
    }

    if (blk < 1280) {
        int x = (blk - 256) * 256 + t;
        for (; x < 800016; x += 1024 * 256) {
            float2 v = ((const float2*)seq_emb)[x];
            seq_h2[x] = __float22half2_rn(v);
        }
        return;
    }

    if (blk < 1284) {
        const int o = (blk - 1280) * 256 + t;
        const int j = o >> 5, e = o & 31;
        float sm = 0.f;
#pragma unroll 8
        for (int a = 0; a < A_; ++a) sm += Wv[j * A_ + a] * Wo[a * E_ + e];
        M[o] = sm;
        return;
    }

    if (blk < 1348) {
        int x = (blk - 1284) * 256 + t;
        for (; x < 65536; x += 64 * 256) {
            W12_1[x] = __float22half2_rn(make_float2(q1W1[x], q1W2[x]));
            W12_2[x] = __float22half2_rn(make_float2(q2W1[x], q2W2[x]));
        }
        return;
    }

    {
        int x = (blk - 1348) * 256 + t;
        for (; x < 16384; x += 8 * 256)
            Wmlp_h2[x] = __float22half2_rn(((const float2*)Wmlp)[x]);
        // Wp is 256x256 = 32768 float2 — FULL conversion (R4-R9 did 16384).
        x = (blk - 1348) * 256 + t;
        for (; x < 32768; x += 8 * 256) {
            Wp1_h2[x] = __float22half2_rn(((const float2*)q1Wp)[x]);
            Wp2_h2[x] = __float22half2_rn(((const float2*)q2Wp)[x]);
        }
    }
}

// ---------------------------------------------------------------------------
// K2: score + top-30 + softmax + interest + MLP, fused.  256 blocks x 512.
// R9 structure, but `part` is now a SINGLE 32 KB buffer (dual-GEMV reduces
// t1 and t2 sequentially, a2 held in registers across the barrier).
// LDS ~60 KB -> 2 blocks/CU (was 92 KB -> 1 block/CU).
// ---------------------------------------------------------------------------
#define RM 4
__global__ __launch_bounds__(512) void score_mlp_kernel(
    const int* __restrict__ seqs, const __half* __restrict__ seq_h,
    const float* __restrict__ seq_emb, const float* __restrict__ p,
    const float* __restrict__ M, const float* __restrict__ bo,
    const float* __restrict__ fused,
    const __half* __restrict__ Wmlp_h, const float* __restrict__ bmlp,
    const __half2* __restrict__ W12_1, const float* __restrict__ b11,
    const float* __restrict__ b12, const __half* __restrict__ Wp1_h,
    const float* __restrict__ b1p,
    const __half2* __restrict__ W12_2, const float* __restrict__ b21,
    const float* __restrict__ b22, const __half* __restrict__ Wp2_h,
    const float* __restrict__ b2p,
    const float* __restrict__ Wout, const float* __restrict__ bout,
    float* __restrict__ out)
{
    const int b0 = blockIdx.x * RM;
    const int tid = threadIdx.x;

    __shared__ float sc[RM][L_];        // 16 KB (score rows; reused as ebar)
    __shared__ float ps[RM][E_];
    __shared__ float sw[RM][32];
    __shared__ int   stok[RM][32];
    __shared__ float xs[RM][128];
    __shared__ float hs[RM][H_];
    __shared__ float ts[RM][H_];
    __shared__ float part[8][RM][H_];   // 32 KB single buffer
    __shared__ float red[8];

    if (tid < 128) ps[tid >> 5][tid & 31] = p[(b0 + (tid >> 5)) * 32 + (tid & 31)];
    __syncthreads();

    // ---- Phase A: scores. row = tid>>7, 128 threads/row, 8 tokens/thread
    {
        const int row = tid >> 7;
        const int s = tid & 127;
        const int bb = b0 + row;
#pragma unroll
        for (int jj = 0; jj < 4; ++jj) {
            const int l1 = jj * 256 + s;
            const int l2 = l1 + 128;
            const int tok1 = seqs[bb * L_ + l1];
            const int tok2 = seqs[bb * L_ + l2];
            float4 buf[2][4];
            const float4* r1 = (const float4*)(seq_h + (size_t)tok1 * 32);
            const float4* r2 = (const float4*)(seq_h + (size_t)tok2 * 32);
#pragma unroll
            for (int i = 0; i < 4; ++i) buf[0][i] = r1[i];
#pragma unroll
            for (int i = 0; i < 4; ++i) buf[1][i] = r2[i];

            float acc0 = 0.f, acc1 = 0.f;
#pragma unroll
            for (int i = 0; i < 4; ++i) {
                const __half2* h1 = (const __half2*)&buf[0][i];
                const __half2* h2 = (const __half2*)&buf[1][i];
#pragma unroll
                for (int u = 0; u < 4; ++u) {
                    float2 f1 = __half22float2(h1[u]);
                    float2 f2 = __half22float2(h2[u]);
                    acc0 += f1.x * ps[row][i * 8 + 2 * u] + f1.y * ps[row][i * 8 + 2 * u + 1];
                    acc1 += f2.x * ps[row][i * 8 + 2 * u] + f2.y * ps[row][i * 8 + 2 * u + 1];
                }
            }
            sc[row][l1] = acc0 * INV_SQRT_A;
            sc[row][l2] = acc1 * INV_SQRT_A;
        }
    }
    // xs cols 0-31 and 64-127 from K1's fused (interest cols filled below)
    if (tid < 384) {
        const int r = tid / 96, c0 = tid % 96;
        const int c = (c0 < 32) ? c0 : (c0 + 32);
        xs[r][c] = fused[(b0 + r) * 128 + c];
    }
    __syncthreads();

    // ---- Phase B: selection, one row per wave (waves 0-3). R9-proven.
    if (tid < 256) {
        const int w = tid >> 6;
        const int lane = tid & 63;
        const int bb = b0 + w;

        unsigned long long key[16];
#pragma unroll
        for (int j = 0; j < 16; ++j) {
            const int l = j * 64 + lane;
            key[j] = ((unsigned long long)sortable(sc[w][l]) << 10)
                   | (unsigned)(1023 - l);
        }
#pragma unroll
        for (int a = 0; a < 15; ++a)
#pragma unroll
            for (int j = 0; j < 15 - a; ++j) {
                const bool swp = key[j] < key[j + 1];
                const unsigned long long hi = swp ? key[j + 1] : key[j];
                const unsigned long long lo = swp ? key[j] : key[j + 1];
                key[j] = hi; key[j + 1] = lo;
            }

        float myv = -1e30f; int myl = 0;
        unsigned long long front = key[0];
        for (int k = 0; k < TOPK_; ++k) {
            unsigned long long wk = front;
#pragma unroll
            for (int off = 32; off > 0; off >>= 1) {
                unsigned long long o = __shfl_xor(wk, off);
                if (o > wk) wk = o;
            }
            if (lane == k) {
                myv = unsortable((unsigned)(wk >> 10));
                myl = 1023 - (int)(wk & 1023);
            }
            if (front == wk) {
#pragma unroll
                for (int j = 0; j < 15; ++j) key[j] = key[j + 1];
                key[15] = 0ULL;
                front = key[0];
            }
        }

        float m = myv;
#pragma unroll
        for (int off = 32; off > 0; off >>= 1) m = fmaxf(m, __shfl_xor(m, off));
        float e = (lane < TOPK_) ? expf(myv - m) : 0.f;
        float s = e;
#pragma unroll
        for (int off = 32; off > 0; off >>= 1) s += __shfl_xor(s, off);
        if (lane < TOPK_) {
            sw[w][lane]   = e / s;
            stok[w][lane] = seqs[bb * L_ + myl];
        }

        if (lane < E_) {
            float acc = 0.f;
#pragma unroll
            for (int k = 0; k < TOPK_; ++k)
                acc += sw[w][k] * seq_emb[(size_t)stok[w][k] * 32 + lane];
            sc[w][lane] = acc;   // ebar (sc row free now; same-wave r/w)
        }
        if (lane < E_) {
            float acc = bo[lane];
#pragma unroll
            for (int j = 0; j < E_; ++j) acc += sc[w][j] * M[j * E_ + lane];
            xs[w][32 + lane] = acc;   // interest -> LDS
        }
    }
    __syncthreads();

    // ---- Phase C: MLP, single-buffer part.
    const int cg = tid & 63;
    const int iseg = tid >> 6;
    const int c0 = cg * 4;

    {
        float4 acc[RM];
#pragma unroll
        for (int r = 0; r < RM; ++r) acc[r] = make_float4(0.f, 0.f, 0.f, 0.f);
        const int i0 = iseg * 16;
#pragma unroll
        for (int iq = 0; iq < 4; ++iq) {
            const int i = i0 + iq * 4;
            float4 w[4], xv[RM];
#pragma unroll
            for (int u = 0; u < 4; ++u) w[u] = ldh4(Wmlp_h + (i + u) * H_ + c0);
#pragma unroll
            for (int r = 0; r < RM; ++r) xv[r] = *(const float4*)(&xs[r][i]);
#pragma unroll
            for (int r = 0; r < RM; ++r) {
                fma4(acc[r], xv[r].x, w[0]); fma4(acc[r], xv[r].y, w[1]);
                fma4(acc[r], xv[r].z, w[2]); fma4(acc[r], xv[r].w, w[3]);
            }
        }
#pragma unroll
        for (int r = 0; r < RM; ++r) *(float4*)&part[iseg][r][c0] = acc[r];
    }
    __syncthreads();
    for (int o = tid; o < RM * H_; o += 512) {
        const int r = o >> 8, c = o & 255;
        float s = bmlp[c];
#pragma unroll
        for (int sg = 0; sg < 8; ++sg) s += part[sg][r][c];
        hs[r][c] = fmaxf(s, 0.f);
    }
    __syncthreads();

    const __half2* W12s[2] = { W12_1, W12_2 };
    const float* b1s[2] = { b11, b21 }; const float* b2s[2] = { b12, b22 };
    const __half* Wps[2] = { Wp1_h, Wp2_h }; const float* bps[2] = { b1p, b2p };

    for (int q = 0; q < 2; ++q) {
        const __half2* __restrict__ W12 = W12s[q];
        const __half*  __restrict__ Wp  = Wps[q];
        float4 a1[RM], a2[RM];
        {
#pragma unroll
            for (int r = 0; r < RM; ++r) {
                a1[r] = make_float4(0.f, 0.f, 0.f, 0.f);
                a2[r] = make_float4(0.f, 0.f, 0.f, 0.f);
            }
            const int i0 = iseg * 32;
#pragma unroll 2
            for (int iq = 0; iq < 8; ++iq) {
                const int i = i0 + iq * 4;
                float4 w1[4], w2[4], hv[RM];
#pragma unroll
                for (int u = 0; u < 4; ++u) ldh24(W12 + (i + u) * H_ + c0, w1[u], w2[u]);
#pragma unroll
                for (int r = 0; r < RM; ++r) hv[r] = *(const float4*)(&hs[r][i]);
#pragma unroll
                for (int r = 0; r < RM; ++r) {
                    fma4(a1[r], hv[r].x, w1[0]); fma4(a1[r], hv[r].y, w1[1]);
                    fma4(a1[r], hv[r].z, w1[2]); fma4(a1[r], hv[r].w, w1[3]);
                    fma4(a2[r], hv[r].x, w2[0]); fma4(a2[r], hv[r].y, w2[1]);
                    fma4(a2[r], hv[r].z, w2[2]); fma4(a2[r], hv[r].w, w2[3]);
                }
            }
        }
        // t1 via part (a2 stays in registers across the barriers)
#pragma unroll
        for (int r = 0; r < RM; ++r) *(float4*)&part[iseg][r][c0] = a1[r];
        __syncthreads();
        {
            const float* b1 = b1s[q];
            for (int o = tid; o < RM * H_; o += 512) {
                const int r = o >> 8, c = o & 255;
                float t1 = b1[c];
#pragma unroll
                for (int sg = 0; sg < 8; ++sg) t1 += part[sg][r][c];
                ts[r][c] = t1;
            }
        }
        __syncthreads();
        // t2 via part, multiply into ts
#pragma unroll
        for (int r = 0; r < RM; ++r) *(float4*)&part[iseg][r][c0] = a2[r];
        __syncthreads();
        {
            const float* b2 = b2s[q];
            for (int o = tid; o < RM * H_; o += 512) {
                const int r = o >> 8, c = o & 255;
                float t2 = b2[c];
#pragma unroll
                for (int sg = 0; sg < 8; ++sg) t2 += part[sg][r][c];
                ts[r][c] = ts[r][c] * t2;
            }
        }
        __syncthreads();

        // projection: hs += ts @ Wp + bp
        {
            float4 ap[RM];
#pragma unroll
            for (int r = 0; r < RM; ++r) ap[r] = make_float4(0.f, 0.f, 0.f, 0.f);
            const int i0 = iseg * 32;
#pragma unroll 2
            for (int iq = 0; iq < 8; ++iq) {
                const int i = i0 + iq * 4;
                float4 w[4], tv[RM];
#pragma unroll
                for (int u = 0; u < 4; ++u) w[u] = ldh4(Wp + (i + u) * H_ + c0);
#pragma unroll
                for (int r = 0; r < RM; ++r) tv[r] = *(const float4*)(&ts[r][i]);
#pragma unroll
                for (int r = 0; r < RM; ++r) {
                    fma4(ap[r], tv[r].x, w[0]); fma4(ap[r], tv[r].y, w[1]);
                    fma4(ap[r], tv[r].z, w[2]); fma4(ap[r], tv[r].w, w[3]);
                }
            }
#pragma unroll
            for (int r = 0; r < RM; ++r) *(float4*)&part[iseg][r][c0] = ap[r];
        }
        __syncthreads();
        {
            const float* bp = bps[q];
            for (int o = tid; o < RM * H_; o += 512) {
                const int r = o >> 8, c = o & 255;
                float s = bp[c];
#pragma unroll
                for (int sg = 0; sg < 8; ++sg) s += part[sg][r][c];
                hs[r][c] += s;
            }
        }
        __syncthreads();
    }

    {
        const int r = tid >> 7, jj = tid & 127;
        float sum = hs[r][jj] * Wout[jj] + hs[r][jj + 128] * Wout[jj + 128];
#pragma unroll
        for (int off = 32; off > 0; off >>= 1) sum += __shfl_down(sum, off);
        if ((tid & 63) == 0) red[tid >> 6] = sum;
        __syncthreads();
        if (tid < RM) out[b0 + tid] = red[2 * tid] + red[2 * tid + 1] + bout[0];
    }
}

// ---------------------------------------------------------------------------
extern "C" void kernel_launch(void* const* d_in, const int* in_sizes, int n_in,
                              void* d_out, int out_size, void* d_ws, size_t ws_size,
                              hipStream_t stream) {
    const int*   cats    = (const int*)d_in[0];
    const float* nums    = (const float*)d_in[1];
    const int*   seqs    = (const int*)d_in[2];
    const int*   tgt_ids = (const int*)d_in[3];
    const float* cat_emb = (const float*)d_in[4];
    const float* seq_emb = (const float*)d_in[5];
    const float* Wnum    = (const float*)d_in[6];
    const float* bnum    = (const float*)d_in[7];
    const float* Wq      = (const float*)d_in[8];
    const float* Wk      = (const float*)d_in[9];
    const float* Wv      = (const float*)d_in[10];
    const float* Wo      = (const float*)d_in[11];
    const float* bo      = (const float*)d_in[12];
    const float* Wpool   = (const float*)d_in[13];
    const float* bpool   = (const float*)d_in[14];
    const float* Wmlp    = (const float*)d_in[15];
    const float* bmlp    = (const float*)d_in[16];
    const float* q1_W1   = (const float*)d_in[17];
    const float* q1_b1   = (const float*)d_in[18];
    const float* q1_W2   = (const float*)d_in[19];
    const float* q1_b2   = (const float*)d_in[20];
    const float* q1_Wp   = (const float*)d_in[21];
    const float* q1_bp   = (const float*)d_in[22];
    const float* q2_W1   = (const float*)d_in[23];
    const float* q2_b1   = (const float*)d_in[24];
    const float* q2_W2   = (const float*)d_in[25];
    const float* q2_b2   = (const float*)d_in[26];
    const float* q2_Wp   = (const float*)d_in[27];
    const float* q2_bp   = (const float*)d_in[28];
    const float* Wout    = (const float*)d_in[29];
    const float* bout    = (const float*)d_in[30];

    // Workspace layout (float-slot offsets); one half2 == one 4 B slot.
    // seq_h2 needs 800064 slots; Wp buffers need 32768 slots EACH (full Wp).
    float* ws = (float*)d_ws;
    float*   p       = ws;                         //      0 .. 32768
    float*   fused   = ws + 32768;                 //  32768 .. 163840
    float*   M       = ws + 163840;                // 163840 .. 164864
    __half2* seq_h2  = (__half2*)(ws + 164864);    // 164864 .. 964928 (800064)
    __half2* Wmlp_h2 = (__half2*)(ws + 964928);    // 964928 .. 981312
    __half2* W12_1   = (__half2*)(ws + 981312);    // 981312 .. 1046848
    __half2* W12_2   = (__half2*)(ws + 1046848);   // 1046848 .. 1112384
    __half2* Wp1_h2  = (__half2*)(ws + 1112384);   // 1112384 .. 1145152 (32768)
    __half2* Wp2_h2  = (__half2*)(ws + 1145152);   // 1145152 .. 1177920 (32768)

    float* out = (float*)d_out;

    fused_prep_kernel<<<K1_GRID, 256, 0, stream>>>(
        cats, nums, tgt_ids, cat_emb, Wnum, bnum, Wq, Wk, Wv, Wo,
        Wpool, bpool, seq_emb, Wmlp,
        q1_W1, q1_W2, q2_W1, q2_W2, q1_Wp, q2_Wp,
        p, fused, M, seq_h2, Wmlp_h2, W12_1, W12_2, Wp1_h2, Wp2_h2);

    score_mlp_kernel<<<B_ / RM, 512, 0, stream>>>(
        seqs, (const __half*)seq_h2, seq_emb, p, M, bo, fused,
        (const __half*)Wmlp_h2, bmlp,
        W12_1, q1_b1, q1_b2, (const __half*)Wp1_h2, q1_bp,
        W12_2, q2_b1, q2_b2, (const __half*)Wp2_h2, q2_bp,
        Wout, bout, out);
}